// Round 24
// baseline (210.962 us; speedup 1.0000x reference)
//
#include <hip/hip_runtime.h>
#include <hip/hip_bf16.h>
#include <math.h>

// Problem constants: b=4, C=256, H=W=64
#define NPOS 4096
#define CPB  1048576
// ws layout (float offsets)
#define QOFF  ((size_t)0)          // v_t bf16 (2.097M fl) + ml3 + ml2
#define KOFF  ((size_t)4194304)    // head3 opart bf16
#define VOFF  ((size_t)8388608)    // h1 spart (2M fl) + head2 opart bf16
#define AOFF  ((size_t)12582912)   // bf16 att, [b][pos][c]
#define S0OFF ((size_t)16777216)   // q_t + k_t + h0 Spart
#define WTOFF ((size_t)21250048)   // bf16 W2 [k][o][c]
#define QTOFF   S0OFF
#define KTOFF   (S0OFF + (size_t)2097152)
#define SP0OFF  (S0OFF + (size_t)4194304)
#define VTOFF   QOFF
#define ML3OFF  (QOFF + (size_t)2097152)
#define ML2OFF  (QOFF + (size_t)2228224)
#define OP3OFF  KOFF
#define SP1OFF  VOFF
#define OP2OFF  (VOFF + (size_t)2097152)

#define LOG2E 1.44269504088896340736f

typedef __attribute__((ext_vector_type(8))) short bf16x8;
typedef __attribute__((ext_vector_type(4))) float f32x4;

static __device__ __forceinline__ unsigned short f2bf(float f) {
  __hip_bfloat16 h = __float2bfloat16(f);
  unsigned short u;
  __builtin_memcpy(&u, &h, sizeof(u));
  return u;
}

static __device__ __forceinline__ float bf2f(unsigned short u) {
  unsigned v = ((unsigned)u) << 16;
  float f;
  __builtin_memcpy(&f, &v, sizeof(f));
  return f;
}

// ---------------------------------------------------------------------------
// Scatter helpers (proven round 13).
template<int PH, int PW>
__device__ __forceinline__ void scat_qk(unsigned short* __restrict__ dst,
                                        const unsigned short* __restrict__ Ac,
                                        int gh, int tid) {
  constexpr int PP = PH * PW, OW = 64 / PW, D = 64 * PP;
  int po = gh / PH, y = gh % PH;
  constexpr int NCH = 64 * OW;
#pragma unroll
  for (int j = 0; j < NCH / 256; ++j) {
    int id = j * 256 + tid;
    int c = id / OW, qo = id % OW;
    int tt = po * OW + qo;
    unsigned short buf[PW];
#pragma unroll
    for (int x = 0; x < PW; ++x) buf[x] = Ac[c * 66 + qo * PW + x];
    unsigned short* dp = &dst[(size_t)tt * D + c * PP + y * PW];
    if constexpr (PW == 8)      { uint4 v;  __builtin_memcpy(&v, buf, 16); *(uint4*)dp = v; }
    else if constexpr (PW == 4) { uint2 v;  __builtin_memcpy(&v, buf, 8);  *(uint2*)dp = v; }
    else                        { unsigned v; __builtin_memcpy(&v, buf, 4); *(unsigned*)dp = v; }
  }
}

template<int PH, int PW>
__device__ __forceinline__ void scat_v(unsigned short* __restrict__ dst,
                                       const unsigned short* __restrict__ Ac,
                                       int gh, int tid) {
  constexpr int PP = PH * PW, OW = 64 / PW, NT = 4096 / PP;
  int po = gh / PH, y = gh % PH;
  constexpr int NCH = 64 * PW;
  constexpr int CPT = (NCH + 255) / 256;
#pragma unroll
  for (int j = 0; j < CPT; ++j) {
    int id = j * 256 + tid;
    if (NCH < 256 && id >= NCH) break;
    int c = id / PW, x = id % PW;
    int d = c * PP + y * PW + x;
    unsigned short* dp = &dst[(size_t)d * NT + po * OW];
#pragma unroll
    for (int s = 0; s < OW; s += 8) {
      unsigned short buf[8];
#pragma unroll
      for (int e = 0; e < 8; ++e) buf[e] = Ac[c * 66 + (s + e) * PW + x];
      uint4 v; __builtin_memcpy(&v, buf, 16);
      *(uint4*)&dp[s] = v;
    }
  }
}

// ---------------------------------------------------------------------------
// Fused QKV projections (q pre-scaled for heads 2/3) + Wo transpose (z=12).
// grid (64 rows, 4 heads, 13). (proven round 17)
__global__ __launch_bounds__(256) void qkv_fused(
    const float* __restrict__ x,
    const float* __restrict__ Wq, const float* __restrict__ Wk, const float* __restrict__ Wv,
    const float* __restrict__ bq, const float* __restrict__ bk, const float* __restrict__ bv,
    const float* __restrict__ Wo, unsigned short* __restrict__ W2,
    unsigned short* __restrict__ qt, unsigned short* __restrict__ kt_,
    unsigned short* __restrict__ vt) {
  if (blockIdx.z == 12) {
    int o = blockIdx.y * 64 + blockIdx.x;
    size_t base = (size_t)o * 2304;
#pragma unroll
    for (int r = 0; r < 9; ++r) {
      int rr = r * 256 + threadIdx.x;
      int c = rr / 9, k = rr % 9;
      W2[(size_t)k * 65536 + (size_t)o * 256 + c] = f2bf(Wo[base + rr]);
    }
    return;
  }
  int b = blockIdx.z / 3, t = blockIdx.z % 3;
  const float* W    = (t == 0) ? Wq : (t == 1) ? Wk : Wv;
  const float* bias = (t == 0) ? bq : (t == 1) ? bk : bv;
  int h = blockIdx.y, gh = blockIdx.x;
  int o0 = h * 64, p0 = gh * 64;
  __shared__ unsigned short smem[2 * 64 * 72];
  unsigned short* Wt = smem;
  unsigned short* Xs = smem + 64 * 72;
  int tid = threadIdx.x;
  int wv = tid >> 6, l = tid & 63;
  int lg = l >> 4, ll = l & 15;
  f32x4 acc[4];
#pragma unroll
  for (int mi = 0; mi < 4; ++mi) acc[mi] = (f32x4){0.f, 0.f, 0.f, 0.f};

  int wol = tid >> 2, wcp = (tid & 3) * 16;
  int xcc = tid >> 6, xpz = tid & 63;

  for (int c0 = 0; c0 < 256; c0 += 64) {
    __syncthreads();
#pragma unroll
    for (int u = 0; u < 4; ++u) {
      float4 w4 = *(const float4*)&W[(size_t)(o0 + wol) * 256 + c0 + wcp + u * 4];
      ushort4 pk;
      pk.x = f2bf(w4.x); pk.y = f2bf(w4.y); pk.z = f2bf(w4.z); pk.w = f2bf(w4.w);
      *(ushort4*)&Wt[wol * 72 + wcp + u * 4] = pk;
    }
#pragma unroll
    for (int r = 0; r < 16; ++r) {
      int c = xcc * 16 + r;
      Xs[xpz * 72 + c] = f2bf(x[(size_t)b * CPB + (size_t)(c0 + c) * NPOS + p0 + xpz]);
    }
    __syncthreads();
#pragma unroll
    for (int ks = 0; ks < 2; ++ks) {
      bf16x8 xb = *(const bf16x8*)&Xs[(wv * 16 + ll) * 72 + ks * 32 + lg * 8];
#pragma unroll
      for (int mi = 0; mi < 4; ++mi) {
        bf16x8 wa = *(const bf16x8*)&Wt[(mi * 16 + ll) * 72 + ks * 32 + lg * 8];
        acc[mi] = __builtin_amdgcn_mfma_f32_16x16x32_bf16(wa, xb, acc[mi], 0, 0, 0);
      }
    }
  }
  __syncthreads();
  float qs = 1.0f;
  if (t == 0) qs = (h == 2) ? 0.0625f * LOG2E : (h == 3) ? 0.125f * LOG2E : 1.0f;
  unsigned short* Ac = smem;
#pragma unroll
  for (int mi = 0; mi < 4; ++mi)
#pragma unroll
    for (int r = 0; r < 4; ++r) {
      int ol = mi * 16 + lg * 4 + r;
      Ac[ol * 66 + wv * 16 + ll] = f2bf((acc[mi][r] + bias[o0 + ol]) * qs);
    }
  __syncthreads();
  if (t < 2) {
    unsigned short* dst = (t == 0 ? qt : kt_) + ((size_t)b * 4 + h) * 262144;
    switch (h) {
      case 0: scat_qk<8, 8>(dst, Ac, gh, tid); break;
      case 1: scat_qk<4, 4>(dst, Ac, gh, tid); break;
      case 2: scat_qk<2, 2>(dst, Ac, gh, tid); break;
      default: {
        int p = tid >> 2, c0 = (tid & 3) * 16;
        unsigned short buf[16];
#pragma unroll
        for (int e = 0; e < 16; ++e) buf[e] = Ac[(c0 + e) * 66 + p];
        uint4 v0, v1;
        __builtin_memcpy(&v0, buf, 16);
        __builtin_memcpy(&v1, buf + 8, 16);
        uint4* d4 = (uint4*)&dst[(size_t)(gh * 64 + p) * 64 + c0];
        d4[0] = v0; d4[1] = v1;
      } break;
    }
  } else {
    unsigned short* dst = vt + ((size_t)b * 4 + h) * 262144;
    switch (h) {
      case 0: scat_v<8, 8>(dst, Ac, gh, tid); break;
      case 1: scat_v<4, 4>(dst, Ac, gh, tid); break;
      case 2: scat_v<2, 2>(dst, Ac, gh, tid); break;
      default: {
        if (tid < 64) {
#pragma unroll
          for (int seg = 0; seg < 8; ++seg) {
            unsigned short buf[8];
#pragma unroll
            for (int e = 0; e < 8; ++e) buf[e] = Ac[tid * 66 + seg * 8 + e];
            uint4 v; __builtin_memcpy(&v, buf, 16);
            *(uint4*)&dst[(size_t)tid * 4096 + gh * 64 + seg * 8] = v;
          }
        }
      } break;
    }
  }
}

// ---------------------------------------------------------------------------
// Flash attention body (single-buffer LDS staging, used by flash2 only).
// Bare-exp2 softmax (Q pre-scaled); setprio; bf16 split partials.
// VSTR = KVB+4 (was +8): fits 39936 B LDS; gcd(18,32)=2 bank rotation.
template<int NTOK, int DDIM, int NSPLIT, int KVB, int PH, int PW, int HEAD>
__device__ __forceinline__ void flash_body(
    unsigned char* smem, int b, int q0, int split,
    const unsigned short* __restrict__ qt, const unsigned short* __restrict__ kt_,
    const unsigned short* __restrict__ vt, unsigned short* __restrict__ opart,
    float* __restrict__ ml, unsigned short* __restrict__ attbf) {
  constexpr int KSTR = DDIM + 8;
  constexpr int VSTR = KVB + 4;
  constexpr int NT   = KVB / 16;
  constexpr int KCH  = DDIM / 32;
  constexpr int PKS  = KVB / 32;
  constexpr int OCG  = DDIM / 16;
  constexpr int PP = PH * PW, OW = 64 / PW;
  const unsigned short* Q = qt + ((size_t)b * 4 + HEAD) * 262144;
  const unsigned short* K = kt_ + ((size_t)b * 4 + HEAD) * 262144;
  const unsigned short* V = vt + ((size_t)b * 4 + HEAD) * 262144;
  unsigned short* Ks = (unsigned short*)smem;
  unsigned short* Vs = Ks + KVB * KSTR;
  unsigned short* Psw = Vs + DDIM * VSTR;
  int tid = threadIdx.x;
  int wv = tid >> 6, l = tid & 63;
  int lg = l >> 4, ll = l & 15;
  int qw = q0 + wv * 16;
  unsigned short* Ps = Psw + wv * 16 * VSTR;

  bf16x8 qf[KCH];
#pragma unroll
  for (int kc = 0; kc < KCH; ++kc)
    qf[kc] = *(const bf16x8*)&Q[(size_t)(qw + ll) * DDIM + kc * 32 + lg * 8];

  bf16x8 onesf;
#pragma unroll
  for (int e = 0; e < 8; ++e) onesf[e] = (short)0x3F80;

  f32x4 lacc = (f32x4){0.f, 0.f, 0.f, 0.f};
  f32x4 o_acc[OCG];
#pragma unroll
  for (int c = 0; c < OCG; ++c) o_acc[c] = (f32x4){0.f, 0.f, 0.f, 0.f};

  for (int kt0 = split * (NTOK / NSPLIT); kt0 < (split + 1) * (NTOK / NSPLIT); kt0 += KVB) {
    __syncthreads();
#pragma unroll
    for (int i = 0; i < KVB * DDIM / 2048; ++i) {
      int u = i * 256 + tid;
      int key = u / (DDIM / 8), part = u % (DDIM / 8);
      *(uint4*)&Ks[key * KSTR + part * 8] =
          *(const uint4*)&K[(size_t)(kt0 + key) * DDIM + part * 8];
    }
#pragma unroll
    for (int i = 0; i < KVB * DDIM / 2048; ++i) {
      int u = i * 256 + tid;
      int d = u / (KVB / 8), part = u % (KVB / 8);
      *(uint4*)&Vs[d * VSTR + part * 8] =
          *(const uint4*)&V[(size_t)d * NTOK + kt0 + part * 8];
    }
    __syncthreads();
    f32x4 s_acc[NT];
#pragma unroll
    for (int n = 0; n < NT; ++n) s_acc[n] = (f32x4){0.f, 0.f, 0.f, 0.f};
    __builtin_amdgcn_s_setprio(1);
#pragma unroll
    for (int n = 0; n < NT; ++n)
#pragma unroll
      for (int kc = 0; kc < KCH; ++kc) {
        bf16x8 kf = *(const bf16x8*)&Ks[(n * 16 + ll) * KSTR + kc * 32 + lg * 8];
        s_acc[n] = __builtin_amdgcn_mfma_f32_16x16x32_bf16(qf[kc], kf, s_acc[n], 0, 0, 0);
      }
    __builtin_amdgcn_s_setprio(0);
#pragma unroll
    for (int n = 0; n < NT; ++n)
#pragma unroll
      for (int r = 0; r < 4; ++r)
        Ps[(lg * 4 + r) * VSTR + n * 16 + ll] = f2bf(exp2f(s_acc[n][r]));
    __builtin_amdgcn_s_setprio(1);
#pragma unroll
    for (int pk = 0; pk < PKS; ++pk) {
      bf16x8 pa = *(const bf16x8*)&Ps[ll * VSTR + pk * 32 + lg * 8];
      lacc = __builtin_amdgcn_mfma_f32_16x16x32_bf16(pa, onesf, lacc, 0, 0, 0);
#pragma unroll
      for (int c = 0; c < OCG; ++c) {
        bf16x8 vf = *(const bf16x8*)&Vs[(c * 16 + ll) * VSTR + pk * 32 + lg * 8];
        o_acc[c] = __builtin_amdgcn_mfma_f32_16x16x32_bf16(pa, vf, o_acc[c], 0, 0, 0);
      }
    }
    __builtin_amdgcn_s_setprio(0);
  }
  if constexpr (NSPLIT > 1) {
    size_t ob = (size_t)(b * NSPLIT + split) * NTOK;
#pragma unroll
    for (int r = 0; r < 4; ++r) {
      int q = qw + lg * 4 + r;
#pragma unroll
      for (int c = 0; c < OCG; ++c)
        opart[(ob + q) * DDIM + c * 16 + ll] = f2bf(o_acc[c][r]);
      if (ll == 0) {
        ml[(ob + q) * 2]     = 0.f;
        ml[(ob + q) * 2 + 1] = lacc[r];
      }
    }
  } else {
#pragma unroll
    for (int r = 0; r < 4; ++r) {
      float inv = 1.0f / lacc[r];
      int q = qw + lg * 4 + r;
      int po = q / OW, qo = q % OW;
#pragma unroll
      for (int c = 0; c < OCG; ++c) {
        int d = c * 16 + ll;
        int ch = d / PP, rem = d % PP, y = rem / PW, x = rem % PW;
        int pos = (po * PH + y) * 64 + qo * PW + x;
        attbf[((size_t)b * NPOS + pos) * 256 + HEAD * 64 + ch] = f2bf(o_acc[c][r] * inv);
      }
    }
  }
}

// ---------------------------------------------------------------------------
// Head-3 flash, QBLK=128, K-only LDS double-buffer + V DIRECT from L2 to
// registers: V is consumed AFTER QK+exp2 (~400+ cyc later), so its L2
// latency hides under compute (unlike K, which R19 showed must stay staged).
// LDS: 2x9216 K dbuf + 9216 P = 27648 B -> kernel max 39936 -> 4 blocks/CU.
// kfr/vfr shared by both Q groups (R23). Values bit-identical.
__device__ __forceinline__ void flash3_dbuf(
    unsigned char* smem, int b, int q0, int split,
    const unsigned short* __restrict__ qt, const unsigned short* __restrict__ kt_,
    const unsigned short* __restrict__ vt, unsigned short* __restrict__ opart,
    float* __restrict__ ml) {
  const unsigned short* Q = qt + ((size_t)b * 4 + 3) * 262144;
  const unsigned short* K = kt_ + ((size_t)b * 4 + 3) * 262144;
  const unsigned short* V = vt + ((size_t)b * 4 + 3) * 262144;
  int tid = threadIdx.x;
  int wv = tid >> 6, l = tid & 63;
  int lg = l >> 4, ll = l & 15;
  int qwA = q0 + wv * 16;
  int qwB = qwA + 64;
  unsigned short* Ps = (unsigned short*)(smem + 18432) + wv * 16 * 72;

  bf16x8 qfA[2], qfB[2];
  qfA[0] = *(const bf16x8*)&Q[(size_t)(qwA + ll) * 64 + lg * 8];
  qfA[1] = *(const bf16x8*)&Q[(size_t)(qwA + ll) * 64 + 32 + lg * 8];
  qfB[0] = *(const bf16x8*)&Q[(size_t)(qwB + ll) * 64 + lg * 8];
  qfB[1] = *(const bf16x8*)&Q[(size_t)(qwB + ll) * 64 + 32 + lg * 8];

  bf16x8 onesf;
#pragma unroll
  for (int e = 0; e < 8; ++e) onesf[e] = (short)0x3F80;

  f32x4 laccA = (f32x4){0.f, 0.f, 0.f, 0.f};
  f32x4 laccB = (f32x4){0.f, 0.f, 0.f, 0.f};
  f32x4 o_accA[4], o_accB[4];
#pragma unroll
  for (int c = 0; c < 4; ++c) {
    o_accA[c] = (f32x4){0.f, 0.f, 0.f, 0.f};
    o_accB[c] = (f32x4){0.f, 0.f, 0.f, 0.f};
  }

  const int kstart = split * 1024, kend = kstart + 1024;

  {  // prologue: stage K tile kstart into buffer 0
    unsigned short* Kd = (unsigned short*)smem;
#pragma unroll
    for (int i = 0; i < 2; ++i) {
      int u = i * 256 + tid, row = u >> 3, part = u & 7;
      *(uint4*)&Kd[row * 72 + part * 8] =
          *(const uint4*)&K[(size_t)(kstart + row) * 64 + part * 8];
    }
  }
  __syncthreads();

  int cur = 0;
  for (int kt0 = kstart; kt0 < kend; kt0 += 64) {
    const bool more = (kt0 + 64) < kend;
    if (more) {
      unsigned short* Kd = (unsigned short*)(smem + (cur ^ 1) * 9216);
#pragma unroll
      for (int i = 0; i < 2; ++i) {
        int u = i * 256 + tid, row = u >> 3, part = u & 7;
        *(uint4*)&Kd[row * 72 + part * 8] =
            *(const uint4*)&K[(size_t)(kt0 + 64 + row) * 64 + part * 8];
      }
    }
    unsigned short* Kc = (unsigned short*)(smem + cur * 9216);

    // V fragments direct from L2 (issued early; consumed after QK+exp2)
    bf16x8 vfr[2][4];
#pragma unroll
    for (int pk = 0; pk < 2; ++pk)
#pragma unroll
      for (int c = 0; c < 4; ++c)
        vfr[pk][c] = *(const bf16x8*)&V[(size_t)(c * 16 + ll) * 4096 + kt0 + pk * 32 + lg * 8];
    // K fragments from LDS once per tile (shared by A and B)
    bf16x8 kfr[4][2];
#pragma unroll
    for (int n = 0; n < 4; ++n)
#pragma unroll
      for (int kc = 0; kc < 2; ++kc)
        kfr[n][kc] = *(const bf16x8*)&Kc[(n * 16 + ll) * 72 + kc * 32 + lg * 8];

    // ---- group A ----
    {
      f32x4 s_acc[4];
#pragma unroll
      for (int n = 0; n < 4; ++n) s_acc[n] = (f32x4){0.f, 0.f, 0.f, 0.f};
      __builtin_amdgcn_s_setprio(1);
#pragma unroll
      for (int n = 0; n < 4; ++n)
#pragma unroll
        for (int kc = 0; kc < 2; ++kc)
          s_acc[n] = __builtin_amdgcn_mfma_f32_16x16x32_bf16(qfA[kc], kfr[n][kc], s_acc[n],
                                                             0, 0, 0);
      __builtin_amdgcn_s_setprio(0);
#pragma unroll
      for (int n = 0; n < 4; ++n)
#pragma unroll
        for (int r = 0; r < 4; ++r)
          Ps[(lg * 4 + r) * 72 + n * 16 + ll] = f2bf(exp2f(s_acc[n][r]));
      __builtin_amdgcn_s_setprio(1);
#pragma unroll
      for (int pk = 0; pk < 2; ++pk) {
        bf16x8 pa = *(const bf16x8*)&Ps[ll * 72 + pk * 32 + lg * 8];
        laccA = __builtin_amdgcn_mfma_f32_16x16x32_bf16(pa, onesf, laccA, 0, 0, 0);
#pragma unroll
        for (int c = 0; c < 4; ++c)
          o_accA[c] = __builtin_amdgcn_mfma_f32_16x16x32_bf16(pa, vfr[pk][c], o_accA[c],
                                                              0, 0, 0);
      }
      __builtin_amdgcn_s_setprio(0);
    }
    // ---- group B (reuses Ps after A's PV reads; same-wave DS ordering) ----
    {
      f32x4 s_acc[4];
#pragma unroll
      for (int n = 0; n < 4; ++n) s_acc[n] = (f32x4){0.f, 0.f, 0.f, 0.f};
      __builtin_amdgcn_s_setprio(1);
#pragma unroll
      for (int n = 0; n < 4; ++n)
#pragma unroll
        for (int kc = 0; kc < 2; ++kc)
          s_acc[n] = __builtin_amdgcn_mfma_f32_16x16x32_bf16(qfB[kc], kfr[n][kc], s_acc[n],
                                                             0, 0, 0);
      __builtin_amdgcn_s_setprio(0);
#pragma unroll
      for (int n = 0; n < 4; ++n)
#pragma unroll
        for (int r = 0; r < 4; ++r)
          Ps[(lg * 4 + r) * 72 + n * 16 + ll] = f2bf(exp2f(s_acc[n][r]));
      __builtin_amdgcn_s_setprio(1);
#pragma unroll
      for (int pk = 0; pk < 2; ++pk) {
        bf16x8 pa = *(const bf16x8*)&Ps[ll * 72 + pk * 32 + lg * 8];
        laccB = __builtin_amdgcn_mfma_f32_16x16x32_bf16(pa, onesf, laccB, 0, 0, 0);
#pragma unroll
        for (int c = 0; c < 4; ++c)
          o_accB[c] = __builtin_amdgcn_mfma_f32_16x16x32_bf16(pa, vfr[pk][c], o_accB[c],
                                                              0, 0, 0);
      }
      __builtin_amdgcn_s_setprio(0);
    }
    __syncthreads();
    cur ^= 1;
  }
  size_t ob = (size_t)(b * 4 + split) * 4096;
#pragma unroll
  for (int r = 0; r < 4; ++r) {
    int qA = qwA + lg * 4 + r;
    int qB = qwB + lg * 4 + r;
#pragma unroll
    for (int c = 0; c < 4; ++c) {
      opart[(ob + qA) * 64 + c * 16 + ll] = f2bf(o_accA[c][r]);
      opart[(ob + qB) * 64 + c * 16 + ll] = f2bf(o_accB[c][r]);
    }
    if (ll == 0) {
      ml[(ob + qA) * 2]     = 0.f;
      ml[(ob + qA) * 2 + 1] = laccA[r];
      ml[(ob + qB) * 2]     = 0.f;
      ml[(ob + qB) * 2 + 1] = laccB[r];
    }
  }
}

// ---------------------------------------------------------------------------
// Head 0/1 score bodies (proven round 13; h1 Kc split into 2x128-row halves
// to fit 39936 B LDS — same s_acc<->key mapping, bit-identical accumulation).
__device__ __forceinline__ void h0_score_body(unsigned char* smem, int b, int ds,
                                              const unsigned short* __restrict__ qt,
                                              const unsigned short* __restrict__ kt_,
                                              float* __restrict__ spart) {
  const unsigned short* Q = qt + ((size_t)b * 4 + 0) * 262144;
  const unsigned short* K = kt_ + ((size_t)b * 4 + 0) * 262144;
  unsigned short* Qc = (unsigned short*)smem;
  unsigned short* Kc = Qc + 64 * 72;
  int tid = threadIdx.x;
  int wv = tid >> 6, l = tid & 63;
  int lg = l >> 4, ll = l & 15;
  f32x4 s_acc[4];
#pragma unroll
  for (int n = 0; n < 4; ++n) s_acc[n] = (f32x4){0.f, 0.f, 0.f, 0.f};
  for (int ch = 0; ch < 8; ++ch) {
    int d0 = ds * 512 + ch * 64;
    __syncthreads();
#pragma unroll
    for (int i = 0; i < 2; ++i) {
      int u = i * 256 + tid, row = u >> 3, part = u & 7;
      *(uint4*)&Qc[row * 72 + part * 8] = *(const uint4*)&Q[(size_t)row * 4096 + d0 + part * 8];
      *(uint4*)&Kc[row * 72 + part * 8] = *(const uint4*)&K[(size_t)row * 4096 + d0 + part * 8];
    }
    __syncthreads();
#pragma unroll
    for (int n = 0; n < 4; ++n)
#pragma unroll
      for (int ks = 0; ks < 2; ++ks) {
        bf16x8 qa = *(const bf16x8*)&Qc[(wv * 16 + ll) * 72 + ks * 32 + lg * 8];
        bf16x8 kf = *(const bf16x8*)&Kc[(n * 16 + ll) * 72 + ks * 32 + lg * 8];
        s_acc[n] = __builtin_amdgcn_mfma_f32_16x16x32_bf16(qa, kf, s_acc[n], 0, 0, 0);
      }
  }
#pragma unroll
  for (int n = 0; n < 4; ++n)
#pragma unroll
    for (int r = 0; r < 4; ++r)
      spart[(((size_t)b * 8 + ds) * 64 + (wv * 16 + lg * 4 + r)) * 64 + n * 16 + ll] =
          s_acc[n][r];
}

__device__ __forceinline__ void h1_score_body(unsigned char* smem, int b, int qtile, int ds,
                                              const unsigned short* __restrict__ qt,
                                              const unsigned short* __restrict__ kt_,
                                              float* __restrict__ spart) {
  int q0 = qtile * 64, dbase = ds * 128;
  const unsigned short* Q = qt + ((size_t)b * 4 + 1) * 262144;
  const unsigned short* K = kt_ + ((size_t)b * 4 + 1) * 262144;
  unsigned short* Qc = (unsigned short*)smem;
  unsigned short* Kc = Qc + 64 * 72;   // 128 rows * 72 -> (64+128)*72*2 = 27648 B
  int tid = threadIdx.x;
  int wv = tid >> 6, l = tid & 63;
  int lg = l >> 4, ll = l & 15;
  f32x4 s_acc[16];
#pragma unroll
  for (int n = 0; n < 16; ++n) s_acc[n] = (f32x4){0.f, 0.f, 0.f, 0.f};
  for (int dc = 0; dc < 2; ++dc) {
    int d0 = dbase + dc * 64;
    for (int kh = 0; kh < 2; ++kh) {
      __syncthreads();
      if (kh == 0) {
#pragma unroll
        for (int i = 0; i < 2; ++i) {
          int u = i * 256 + tid, row = u >> 3, part = u & 7;
          *(uint4*)&Qc[row * 72 + part * 8] =
              *(const uint4*)&Q[(size_t)(q0 + row) * 1024 + d0 + part * 8];
        }
      }
#pragma unroll
      for (int i = 0; i < 4; ++i) {
        int u = i * 256 + tid, row = u >> 3, part = u & 7;
        *(uint4*)&Kc[row * 72 + part * 8] =
            *(const uint4*)&K[(size_t)(kh * 128 + row) * 1024 + d0 + part * 8];
      }
      __syncthreads();
#pragma unroll
      for (int ks = 0; ks < 2; ++ks) {
        bf16x8 qa = *(const bf16x8*)&Qc[(wv * 16 + ll) * 72 + ks * 32 + lg * 8];
#pragma unroll
        for (int nn = 0; nn < 8; ++nn) {
          bf16x8 kf = *(const bf16x8*)&Kc[(nn * 16 + ll) * 72 + ks * 32 + lg * 8];
          s_acc[kh * 8 + nn] = __builtin_amdgcn_mfma_f32_16x16x32_bf16(qa, kf, s_acc[kh * 8 + nn],
                                                                      0, 0, 0);
        }
      }
    }
  }
#pragma unroll
  for (int n = 0; n < 16; ++n)
#pragma unroll
    for (int r = 0; r < 4; ++r) {
      int q = q0 + wv * 16 + lg * 4 + r;
      spart[(((size_t)b * 8 + ds) * 256 + q) * 256 + n * 16 + ll] = s_acc[n][r];
    }
}

// ---------------------------------------------------------------------------
// Merged attention launch: flash3-dbuf QBLK=128 (bid<512) | flash2
// (512..639) | score01 (640..799). LDS 39936 B -> 4 blocks/CU.
__global__ __launch_bounds__(256) void attn_all(
    const unsigned short* __restrict__ qt, const unsigned short* __restrict__ kt_,
    const unsigned short* __restrict__ vt,
    unsigned short* __restrict__ op2, float* __restrict__ ml2,
    unsigned short* __restrict__ op3, float* __restrict__ ml3,
    float* __restrict__ sp0, float* __restrict__ sp1,
    unsigned short* __restrict__ attbf) {
  __shared__ __align__(16) unsigned char smem[39936];
  int bid = blockIdx.x;
  if (bid < 512) {
    int b = bid & 3, qy = (bid >> 2) & 31, split = bid >> 7;
    flash3_dbuf(smem, b, qy * 128, split, qt, kt_, vt, op3, ml3);
  } else if (bid < 640) {
    int r = bid - 512;
    int b = r & 3, qy = (r >> 2) & 15, split = r >> 6;
    flash_body<1024, 256, 2, 32, 2, 2, 2>(smem, b, qy * 64, split, qt, kt_, vt,
                                          op2, ml2, attbf);
  } else {
    int r = bid - 640;
    if (r < 32) h0_score_body(smem, r >> 3, r & 7, qt, kt_, sp0);
    else {
      int rr = r - 32;
      h1_score_body(smem, rr >> 5, (rr >> 3) & 3, rr & 7, qt, kt_, sp1);
    }
  }
}

// ---------------------------------------------------------------------------
// Head 0/1 pv bodies (proven).
__device__ __forceinline__ void h0_pv_body(unsigned char* smem, int b, int ds,
                                           const float* __restrict__ spart,
                                           const unsigned short* __restrict__ vt,
                                           unsigned short* __restrict__ attbf) {
  const unsigned short* V = vt + ((size_t)b * 4 + 0) * 262144;
  float* S = (float*)smem;
  unsigned short* Ps = (unsigned short*)(smem + 16640);
  unsigned short* Vc = Ps + 64 * 72;
  int tid = threadIdx.x;
  int wv = tid >> 6, l = tid & 63;
  int lg = l >> 4, ll = l & 15;
#pragma unroll
  for (int i = 0; i < 16; ++i) {
    int idx = i * 256 + tid, q = idx >> 6, k = idx & 63;
    float s = 0.f;
#pragma unroll
    for (int sl = 0; sl < 8; ++sl)
      s += spart[(((size_t)b * 8 + sl) * 64 + q) * 64 + k];
    S[q * 65 + k] = s;
  }
  __syncthreads();
  for (int rr = 0; rr < 16; ++rr) {
    int row = wv * 16 + rr;
    float v = S[row * 65 + l] * 0.015625f;
    float m = v;
#pragma unroll
    for (int d = 32; d >= 1; d >>= 1) m = fmaxf(m, __shfl_xor(m, d));
    float p = __expf(v - m);
    float su = p;
#pragma unroll
    for (int d = 32; d >= 1; d >>= 1) su += __shfl_xor(su, d);
    Ps[row * 72 + l] = f2bf(p / su);
  }
  __syncthreads();
  for (int ch = 0; ch < 8; ++ch) {
    int d0 = ds * 512 + ch * 64;
    __syncthreads();
#pragma unroll
    for (int i = 0; i < 2; ++i) {
      int u = i * 256 + tid, row = u >> 3, part = u & 7;
      *(uint4*)&Vc[row * 72 + part * 8] =
          *(const uint4*)&V[(size_t)(d0 + row) * 64 + part * 8];
    }
    __syncthreads();
    f32x4 o[4];
#pragma unroll
    for (int cg = 0; cg < 4; ++cg) o[cg] = (f32x4){0.f, 0.f, 0.f, 0.f};
#pragma unroll
    for (int cg = 0; cg < 4; ++cg)
#pragma unroll
      for (int ks = 0; ks < 2; ++ks) {
        bf16x8 pa = *(const bf16x8*)&Ps[(wv * 16 + ll) * 72 + ks * 32 + lg * 8];
        bf16x8 vf = *(const bf16x8*)&Vc[(cg * 16 + ll) * 72 + ks * 32 + lg * 8];
        o[cg] = __builtin_amdgcn_mfma_f32_16x16x32_bf16(pa, vf, o[cg], 0, 0, 0);
      }
#pragma unroll
    for (int cg = 0; cg < 4; ++cg)
#pragma unroll
      for (int r = 0; r < 4; ++r) {
        int q = wv * 16 + lg * 4 + r;
        int d = d0 + cg * 16 + ll;
        int c = d >> 6, rem = d & 63, y = rem >> 3, x = rem & 7;
        int po = q >> 3, qo = q & 7;
        int pos = (po * 8 + y) * 64 + qo * 8 + x;
        attbf[((size_t)b * NPOS + pos) * 256 + c] = f2bf(o[cg][r]);
      }
  }
}

__device__ __forceinline__ void h1_pv_body(unsigned char* smem, int b, int qtile, int vs,
                                           const float* __restrict__ spart,
                                           const unsigned short* __restrict__ vt,
                                           unsigned short* __restrict__ attbf) {
  int q0 = qtile * 64, dv0 = vs * 128;
  const unsigned short* V = vt + ((size_t)b * 4 + 1) * 262144;
  unsigned short* Ps = (unsigned short*)smem;
  unsigned short* Vs = Ps + 64 * 264;
  int tid = threadIdx.x;
  int wv = tid >> 6, l = tid & 63;
  int lg = l >> 4, ll = l & 15;
  for (int rr = 0; rr < 16; ++rr) {
    int row = q0 + wv * 16 + rr;
    float sv[4];
#pragma unroll
    for (int c4 = 0; c4 < 4; ++c4) {
      float s = 0.f;
#pragma unroll
      for (int sl = 0; sl < 8; ++sl)
        s += spart[(((size_t)b * 8 + sl) * 256 + row) * 256 + c4 * 64 + l];
      sv[c4] = s * 0.03125f;
    }
    float m = fmaxf(fmaxf(sv[0], sv[1]), fmaxf(sv[2], sv[3]));
#pragma unroll
    for (int d = 32; d >= 1; d >>= 1) m = fmaxf(m, __shfl_xor(m, d));
    float p[4], su = 0.f;
#pragma unroll
    for (int c4 = 0; c4 < 4; ++c4) { p[c4] = __expf(sv[c4] - m); su += p[c4]; }
#pragma unroll
    for (int d = 32; d >= 1; d >>= 1) su += __shfl_xor(su, d);
    float inv = 1.0f / su;
#pragma unroll
    for (int c4 = 0; c4 < 4; ++c4)
      Ps[(wv * 16 + rr) * 264 + c4 * 64 + l] = f2bf(p[c4] * inv);
  }
  for (int vc = 0; vc < 4; ++vc) {
    int d0 = dv0 + vc * 32;
    __syncthreads();
#pragma unroll
    for (int i = 0; i < 4; ++i) {
      int u = i * 256 + tid, row = u >> 5, part = u & 31;
      *(uint4*)&Vs[row * 264 + part * 8] =
          *(const uint4*)&V[(size_t)(d0 + row) * 256 + part * 8];
    }
    __syncthreads();
    f32x4 o[2];
    o[0] = (f32x4){0.f, 0.f, 0.f, 0.f};
    o[1] = (f32x4){0.f, 0.f, 0.f, 0.f};
#pragma unroll
    for (int ks = 0; ks < 8; ++ks) {
      bf16x8 pa = *(const bf16x8*)&Ps[(wv * 16 + ll) * 264 + ks * 32 + lg * 8];
#pragma unroll
      for (int cg = 0; cg < 2; ++cg) {
        bf16x8 vf = *(const bf16x8*)&Vs[(cg * 16 + ll) * 264 + ks * 32 + lg * 8];
        o[cg] = __builtin_amdgcn_mfma_f32_16x16x32_bf16(pa, vf, o[cg], 0, 0, 0);
      }
    }
#pragma unroll
    for (int cg = 0; cg < 2; ++cg)
#pragma unroll
      for (int r = 0; r < 4; ++r) {
        int q = q0 + wv * 16 + lg * 4 + r;
        int d = d0 + cg * 16 + ll;
        int c = d >> 4, rem = d & 15, y = rem >> 2, x = rem & 3;
        int po = q >> 4, qo = q & 15;
        int pos = (po * 4 + y) * 64 + qo * 4 + x;
        attbf[((size_t)b * NPOS + pos) * 256 + 64 + c] = f2bf(o[cg][r]);
      }
  }
}

// ---------------------------------------------------------------------------
// Merged finish launch: pv01 (bid<160) | combine23 (160..8351), bf16 partials.
__global__ __launch_bounds__(256) void finish_all(
    const float* __restrict__ sp0, const float* __restrict__ sp1,
    const unsigned short* __restrict__ op2, const float* __restrict__ ml2,
    const unsigned short* __restrict__ op3, const float* __restrict__ ml3,
    const unsigned short* __restrict__ vt, unsigned short* __restrict__ attbf) {
  __shared__ __align__(16) unsigned char smem[50688];
  int bid = blockIdx.x;
  if (bid < 32) { h0_pv_body(smem, bid >> 3, bid & 7, sp0, vt, attbf); return; }
  if (bid < 160) {
    int r = bid - 32;
    h1_pv_body(smem, r >> 5, (r >> 3) & 3, r & 7, sp1, vt, attbf);
    return;
  }
  int cb = bid - 160;
  if (cb < 4096) {  // head 2, NSPLIT=2
    int b = cb >> 10, q = cb & 1023;
    int d = threadIdx.x;
    float num = 0.f, den = 0.f;
#pragma unroll
    for (int s = 0; s < 2; ++s) {
      den += ml2[((size_t)(b * 2 + s) * 1024 + q) * 2 + 1];
      num += bf2f(op2[((size_t)(b * 2 + s) * 1024 + q) * 256 + d]);
    }
    int c = d >> 2, rem = d & 3, y = rem >> 1, x = rem & 1;
    int po = q >> 5, qo = q & 31;
    int pos = (po * 2 + y) * 64 + qo * 2 + x;
    attbf[((size_t)b * NPOS + pos) * 256 + 128 + c] = f2bf(num / den);
  } else {           // head 3, NSPLIT=4
    cb -= 4096;
    int b = cb >> 10, qt4 = cb & 1023;
    int q = qt4 * 4 + (threadIdx.x >> 6), ch = threadIdx.x & 63;
    float num = 0.f, den = 0.f;
#pragma unroll
    for (int s = 0; s < 4; ++s) {
      den += ml3[((size_t)(b * 4 + s) * 4096 + q) * 2 + 1];
      num += bf2f(op3[((size_t)(b * 4 + s) * 4096 + q) * 64 + ch]);
    }
    attbf[((size_t)b * 4096 + q) * 256 + 192 + ch] = f2bf(num / den);
  }
}

// ---------------------------------------------------------------------------
// 3x3 SAME conv (bf16 MFMA implicit GEMM) + BN + LeakyReLU(0.2). (round 17)
__global__ __launch_bounds__(512) void conv_mfma(
    const unsigned short* __restrict__ attbf, const unsigned short* __restrict__ w2,
    const float* __restrict__ bo, const float* __restrict__ gamma,
    const float* __restrict__ beta, const float* __restrict__ rmean,
    const float* __restrict__ rvar, float* __restrict__ out) {
  int hq = blockIdx.x, ot = blockIdx.y, b = blockIdx.z;
  int h0 = hq * 4, o0 = ot * 64;
  __shared__ unsigned short As[4 * 66 * 72];
  __shared__ unsigned short Ws[3 * 64 * 72];
  int tid = threadIdx.x;
  int wi = tid >> 6, l = tid & 63;
  int hrow = wi >> 1, wseg = wi & 1;
  int lg = l >> 4, ll = l & 15;
  const size_t attb = (size_t)b * NPOS * 256;
  f32x4 acc[4][2];
#pragma unroll
  for (int mi = 0; mi < 4; ++mi)
#pragma unroll
    for (int ni = 0; ni < 2; ++ni) acc[mi][ni] = (f32x4){0.f, 0.f, 0.f, 0.f};

  for (int dy = 0; dy < 3; ++dy) {
    for (int c0 = 0; c0 < 256; c0 += 64) {
      __syncthreads();
      if (tid < 256) {
        int rowl = tid >> 6, w = tid & 63;
        int ghh = h0 + dy - 1 + rowl;
        uint4 z = make_uint4(0u, 0u, 0u, 0u);
        uint4 a[8];
        if (ghh >= 0 && ghh < 64) {
          const uint4* src = (const uint4*)(attbf + attb + ((size_t)(ghh * 64 + w) * 256 + c0));
#pragma unroll
          for (int q = 0; q < 8; ++q) a[q] = src[q];
        } else {
#pragma unroll
          for (int q = 0; q < 8; ++q) a[q] = z;
        }
        uint4* dst = (uint4*)&As[(rowl * 66 + 1 + w) * 72];
#pragma unroll
        for (int q = 0; q < 8; ++q) dst[q] = a[q];
        if (w == 0 || w == 63) {
          uint4* dz = (uint4*)&As[(rowl * 66 + ((w == 0) ? 0 : 65)) * 72];
#pragma unroll
          for (int q = 0; q < 8; ++q) dz[q] = z;
        }
      } else {
        int p = tid - 256;
        int dx = p >> 6, ol = p & 63;
        if (dx < 3) {
          const uint4* src = (const uint4*)(w2 + ((size_t)(dy * 3 + dx) * 65536 +
                                                  (size_t)(o0 + ol) * 256 + c0));
          uint4* dst = (uint4*)&Ws[(dx * 64 + ol) * 72];
#pragma unroll
          for (int q = 0; q < 8; ++q) dst[q] = src[q];
        }
      }
      __syncthreads();
#pragma unroll
      for (int dx = 0; dx < 3; ++dx) {
#pragma unroll
        for (int ks = 0; ks < 2; ++ks) {
          bf16x8 af[4];
#pragma unroll
          for (int mi = 0; mi < 4; ++mi)
            af[mi] = *(const bf16x8*)&Ws[(dx * 64 + mi * 16 + ll) * 72 + ks * 32 + lg * 8];
#pragma unroll
          for (int ni = 0; ni < 2; ++ni) {
            bf16x8 bfr = *(const bf16x8*)&As[(hrow * 66 + wseg * 32 + ni * 16 + ll + dx) * 72 +
                                             ks * 32 + lg * 8];
#pragma unroll
            for (int mi = 0; mi < 4; ++mi)
              acc[mi][ni] = __builtin_amdgcn_mfma_f32_16x16x32_bf16(af[mi], bfr, acc[mi][ni],
                                                                    0, 0, 0);
          }
        }
      }
    }
  }
  int h = h0 + hrow;
#pragma unroll
  for (int mi = 0; mi < 4; ++mi) {
#pragma unroll
    for (int r = 0; r < 4; ++r) {
      int o = o0 + mi * 16 + lg * 4 + r;
      float g  = gamma[o] * rsqrtf(rvar[o] + 1e-5f);
      float bb = (bo[o] - rmean[o]) * g + beta[o];
#pragma unroll
      for (int ni = 0; ni < 2; ++ni) {
        float zv = acc[mi][ni][r] * g + bb;
        zv = (zv >= 0.f) ? zv : 0.2f * zv;
        out[((size_t)(b * 256 + o)) * NPOS + h * 64 + wseg * 32 + ni * 16 + ll] = zv;
      }
    }
  }
}

// ---------------------------------------------------------------------------
extern "C" void kernel_launch(void* const* d_in, const int* in_sizes, int n_in,
                              void* d_out, int out_size, void* d_ws, size_t ws_size,
                              hipStream_t stream) {
  (void)in_sizes; (void)n_in; (void)out_size; (void)ws_size;
  const float* x     = (const float*)d_in[0];
  const float* Wq    = (const float*)d_in[1];
  const float* bq    = (const float*)d_in[2];
  const float* Wk    = (const float*)d_in[3];
  const float* bk    = (const float*)d_in[4];
  const float* Wv    = (const float*)d_in[5];
  const float* bv    = (const float*)d_in[6];
  const float* Wo    = (const float*)d_in[7];
  const float* bo    = (const float*)d_in[8];
  const float* gamma = (const float*)d_in[9];
  const float* beta  = (const float*)d_in[10];
  const float* rmean = (const float*)d_in[11];
  const float* rvar  = (const float*)d_in[12];
  float* ws  = (float*)d_ws;
  float* out = (float*)d_out;
  unsigned short* attbf = (unsigned short*)(ws + AOFF);
  unsigned short* w2bf  = (unsigned short*)(ws + WTOFF);
  unsigned short* qt    = (unsigned short*)(ws + QTOFF);
  unsigned short* kt    = (unsigned short*)(ws + KTOFF);
  unsigned short* vt    = (unsigned short*)(ws + VTOFF);
  unsigned short* op2   = (unsigned short*)(ws + OP2OFF);
  unsigned short* op3   = (unsigned short*)(ws + OP3OFF);

  // QKV projections writing q_t/k_t/v_t directly (+ Wo transpose, z=12)
  qkv_fused<<<dim3(64, 4, 13), 256, 0, stream>>>(x, Wq, Wk, Wv, bq, bk, bv,
                                                 Wo, w2bf, qt, kt, vt);

  // all attention compute co-scheduled: flash3 (QBLK=128, K-dbuf + V-direct,
  // 4 blocks/CU) | flash2 | score01
  attn_all<<<800, 256, 0, stream>>>(qt, kt, vt,
                                    op2, ws + ML2OFF,
                                    op3, ws + ML3OFF,
                                    ws + SP0OFF, ws + SP1OFF, attbf);

  // all finish work co-scheduled: pv01 | combine23
  finish_all<<<8352, 256, 0, stream>>>(ws + SP0OFF, ws + SP1OFF,
                                       op2, ws + ML2OFF,
                                       op3, ws + ML3OFF, vt, attbf);

  conv_mfma<<<dim3(16, 4, 4), 512, 0, stream>>>(attbf, w2bf, bo, gamma, beta,
                                                rmean, rvar, out);
}

// Round 25
// 200.180 us; speedup vs baseline: 1.0539x; 1.0539x over previous
//
#include <hip/hip_runtime.h>
#include <hip/hip_bf16.h>
#include <math.h>

// Problem constants: b=4, C=256, H=W=64
#define NPOS 4096
#define CPB  1048576
// ws layout (float offsets)
#define QOFF  ((size_t)0)          // v_t bf16 (2.097M fl) + ml3 + ml2
#define KOFF  ((size_t)4194304)    // head3 opart bf16
#define VOFF  ((size_t)8388608)    // h1 spart (2M fl) + head2 opart bf16
#define AOFF  ((size_t)12582912)   // bf16 att, [b][pos][c]
#define S0OFF ((size_t)16777216)   // q_t + k_t + h0 Spart
#define WTOFF ((size_t)21250048)   // bf16 W2 [k][o][c]
#define QTOFF   S0OFF
#define KTOFF   (S0OFF + (size_t)2097152)
#define SP0OFF  (S0OFF + (size_t)4194304)
#define VTOFF   QOFF
#define ML3OFF  (QOFF + (size_t)2097152)
#define ML2OFF  (QOFF + (size_t)2228224)
#define OP3OFF  KOFF
#define SP1OFF  VOFF
#define OP2OFF  (VOFF + (size_t)2097152)

#define LOG2E 1.44269504088896340736f

typedef __attribute__((ext_vector_type(8))) short bf16x8;
typedef __attribute__((ext_vector_type(4))) float f32x4;

static __device__ __forceinline__ unsigned short f2bf(float f) {
  __hip_bfloat16 h = __float2bfloat16(f);
  unsigned short u;
  __builtin_memcpy(&u, &h, sizeof(u));
  return u;
}

static __device__ __forceinline__ float bf2f(unsigned short u) {
  unsigned v = ((unsigned)u) << 16;
  float f;
  __builtin_memcpy(&f, &v, sizeof(f));
  return f;
}

// ---------------------------------------------------------------------------
// Scatter helpers (proven round 13).
template<int PH, int PW>
__device__ __forceinline__ void scat_qk(unsigned short* __restrict__ dst,
                                        const unsigned short* __restrict__ Ac,
                                        int gh, int tid) {
  constexpr int PP = PH * PW, OW = 64 / PW, D = 64 * PP;
  int po = gh / PH, y = gh % PH;
  constexpr int NCH = 64 * OW;
#pragma unroll
  for (int j = 0; j < NCH / 256; ++j) {
    int id = j * 256 + tid;
    int c = id / OW, qo = id % OW;
    int tt = po * OW + qo;
    unsigned short buf[PW];
#pragma unroll
    for (int x = 0; x < PW; ++x) buf[x] = Ac[c * 66 + qo * PW + x];
    unsigned short* dp = &dst[(size_t)tt * D + c * PP + y * PW];
    if constexpr (PW == 8)      { uint4 v;  __builtin_memcpy(&v, buf, 16); *(uint4*)dp = v; }
    else if constexpr (PW == 4) { uint2 v;  __builtin_memcpy(&v, buf, 8);  *(uint2*)dp = v; }
    else                        { unsigned v; __builtin_memcpy(&v, buf, 4); *(unsigned*)dp = v; }
  }
}

template<int PH, int PW>
__device__ __forceinline__ void scat_v(unsigned short* __restrict__ dst,
                                       const unsigned short* __restrict__ Ac,
                                       int gh, int tid) {
  constexpr int PP = PH * PW, OW = 64 / PW, NT = 4096 / PP;
  int po = gh / PH, y = gh % PH;
  constexpr int NCH = 64 * PW;
  constexpr int CPT = (NCH + 255) / 256;
#pragma unroll
  for (int j = 0; j < CPT; ++j) {
    int id = j * 256 + tid;
    if (NCH < 256 && id >= NCH) break;
    int c = id / PW, x = id % PW;
    int d = c * PP + y * PW + x;
    unsigned short* dp = &dst[(size_t)d * NT + po * OW];
#pragma unroll
    for (int s = 0; s < OW; s += 8) {
      unsigned short buf[8];
#pragma unroll
      for (int e = 0; e < 8; ++e) buf[e] = Ac[c * 66 + (s + e) * PW + x];
      uint4 v; __builtin_memcpy(&v, buf, 16);
      *(uint4*)&dp[s] = v;
    }
  }
}

// ---------------------------------------------------------------------------
// Fused QKV projections (q pre-scaled for heads 2/3) + Wo transpose (z=12).
// grid (64 rows, 4 heads, 13). (proven round 17)
__global__ __launch_bounds__(256) void qkv_fused(
    const float* __restrict__ x,
    const float* __restrict__ Wq, const float* __restrict__ Wk, const float* __restrict__ Wv,
    const float* __restrict__ bq, const float* __restrict__ bk, const float* __restrict__ bv,
    const float* __restrict__ Wo, unsigned short* __restrict__ W2,
    unsigned short* __restrict__ qt, unsigned short* __restrict__ kt_,
    unsigned short* __restrict__ vt) {
  if (blockIdx.z == 12) {
    int o = blockIdx.y * 64 + blockIdx.x;
    size_t base = (size_t)o * 2304;
#pragma unroll
    for (int r = 0; r < 9; ++r) {
      int rr = r * 256 + threadIdx.x;
      int c = rr / 9, k = rr % 9;
      W2[(size_t)k * 65536 + (size_t)o * 256 + c] = f2bf(Wo[base + rr]);
    }
    return;
  }
  int b = blockIdx.z / 3, t = blockIdx.z % 3;
  const float* W    = (t == 0) ? Wq : (t == 1) ? Wk : Wv;
  const float* bias = (t == 0) ? bq : (t == 1) ? bk : bv;
  int h = blockIdx.y, gh = blockIdx.x;
  int o0 = h * 64, p0 = gh * 64;
  __shared__ unsigned short smem[2 * 64 * 72];
  unsigned short* Wt = smem;
  unsigned short* Xs = smem + 64 * 72;
  int tid = threadIdx.x;
  int wv = tid >> 6, l = tid & 63;
  int lg = l >> 4, ll = l & 15;
  f32x4 acc[4];
#pragma unroll
  for (int mi = 0; mi < 4; ++mi) acc[mi] = (f32x4){0.f, 0.f, 0.f, 0.f};

  int wol = tid >> 2, wcp = (tid & 3) * 16;
  int xcc = tid >> 6, xpz = tid & 63;

  for (int c0 = 0; c0 < 256; c0 += 64) {
    __syncthreads();
#pragma unroll
    for (int u = 0; u < 4; ++u) {
      float4 w4 = *(const float4*)&W[(size_t)(o0 + wol) * 256 + c0 + wcp + u * 4];
      ushort4 pk;
      pk.x = f2bf(w4.x); pk.y = f2bf(w4.y); pk.z = f2bf(w4.z); pk.w = f2bf(w4.w);
      *(ushort4*)&Wt[wol * 72 + wcp + u * 4] = pk;
    }
#pragma unroll
    for (int r = 0; r < 16; ++r) {
      int c = xcc * 16 + r;
      Xs[xpz * 72 + c] = f2bf(x[(size_t)b * CPB + (size_t)(c0 + c) * NPOS + p0 + xpz]);
    }
    __syncthreads();
#pragma unroll
    for (int ks = 0; ks < 2; ++ks) {
      bf16x8 xb = *(const bf16x8*)&Xs[(wv * 16 + ll) * 72 + ks * 32 + lg * 8];
#pragma unroll
      for (int mi = 0; mi < 4; ++mi) {
        bf16x8 wa = *(const bf16x8*)&Wt[(mi * 16 + ll) * 72 + ks * 32 + lg * 8];
        acc[mi] = __builtin_amdgcn_mfma_f32_16x16x32_bf16(wa, xb, acc[mi], 0, 0, 0);
      }
    }
  }
  __syncthreads();
  float qs = 1.0f;
  if (t == 0) qs = (h == 2) ? 0.0625f * LOG2E : (h == 3) ? 0.125f * LOG2E : 1.0f;
  unsigned short* Ac = smem;
#pragma unroll
  for (int mi = 0; mi < 4; ++mi)
#pragma unroll
    for (int r = 0; r < 4; ++r) {
      int ol = mi * 16 + lg * 4 + r;
      Ac[ol * 66 + wv * 16 + ll] = f2bf((acc[mi][r] + bias[o0 + ol]) * qs);
    }
  __syncthreads();
  if (t < 2) {
    unsigned short* dst = (t == 0 ? qt : kt_) + ((size_t)b * 4 + h) * 262144;
    switch (h) {
      case 0: scat_qk<8, 8>(dst, Ac, gh, tid); break;
      case 1: scat_qk<4, 4>(dst, Ac, gh, tid); break;
      case 2: scat_qk<2, 2>(dst, Ac, gh, tid); break;
      default: {
        int p = tid >> 2, c0 = (tid & 3) * 16;
        unsigned short buf[16];
#pragma unroll
        for (int e = 0; e < 16; ++e) buf[e] = Ac[(c0 + e) * 66 + p];
        uint4 v0, v1;
        __builtin_memcpy(&v0, buf, 16);
        __builtin_memcpy(&v1, buf + 8, 16);
        uint4* d4 = (uint4*)&dst[(size_t)(gh * 64 + p) * 64 + c0];
        d4[0] = v0; d4[1] = v1;
      } break;
    }
  } else {
    unsigned short* dst = vt + ((size_t)b * 4 + h) * 262144;
    switch (h) {
      case 0: scat_v<8, 8>(dst, Ac, gh, tid); break;
      case 1: scat_v<4, 4>(dst, Ac, gh, tid); break;
      case 2: scat_v<2, 2>(dst, Ac, gh, tid); break;
      default: {
        if (tid < 64) {
#pragma unroll
          for (int seg = 0; seg < 8; ++seg) {
            unsigned short buf[8];
#pragma unroll
            for (int e = 0; e < 8; ++e) buf[e] = Ac[tid * 66 + seg * 8 + e];
            uint4 v; __builtin_memcpy(&v, buf, 16);
            *(uint4*)&dst[(size_t)tid * 4096 + gh * 64 + seg * 8] = v;
          }
        }
      } break;
    }
  }
}

// ---------------------------------------------------------------------------
// Flash attention body (single-buffer LDS staging, used by flash2 only).
// Bare-exp2 softmax (Q pre-scaled); setprio; bf16 split partials.
// VSTR = KVB+4: 39936 B LDS (verified R24).
template<int NTOK, int DDIM, int NSPLIT, int KVB, int PH, int PW, int HEAD>
__device__ __forceinline__ void flash_body(
    unsigned char* smem, int b, int q0, int split,
    const unsigned short* __restrict__ qt, const unsigned short* __restrict__ kt_,
    const unsigned short* __restrict__ vt, unsigned short* __restrict__ opart,
    float* __restrict__ ml, unsigned short* __restrict__ attbf) {
  constexpr int KSTR = DDIM + 8;
  constexpr int VSTR = KVB + 4;
  constexpr int NT   = KVB / 16;
  constexpr int KCH  = DDIM / 32;
  constexpr int PKS  = KVB / 32;
  constexpr int OCG  = DDIM / 16;
  constexpr int PP = PH * PW, OW = 64 / PW;
  const unsigned short* Q = qt + ((size_t)b * 4 + HEAD) * 262144;
  const unsigned short* K = kt_ + ((size_t)b * 4 + HEAD) * 262144;
  const unsigned short* V = vt + ((size_t)b * 4 + HEAD) * 262144;
  unsigned short* Ks = (unsigned short*)smem;
  unsigned short* Vs = Ks + KVB * KSTR;
  unsigned short* Psw = Vs + DDIM * VSTR;
  int tid = threadIdx.x;
  int wv = tid >> 6, l = tid & 63;
  int lg = l >> 4, ll = l & 15;
  int qw = q0 + wv * 16;
  unsigned short* Ps = Psw + wv * 16 * VSTR;

  bf16x8 qf[KCH];
#pragma unroll
  for (int kc = 0; kc < KCH; ++kc)
    qf[kc] = *(const bf16x8*)&Q[(size_t)(qw + ll) * DDIM + kc * 32 + lg * 8];

  bf16x8 onesf;
#pragma unroll
  for (int e = 0; e < 8; ++e) onesf[e] = (short)0x3F80;

  f32x4 lacc = (f32x4){0.f, 0.f, 0.f, 0.f};
  f32x4 o_acc[OCG];
#pragma unroll
  for (int c = 0; c < OCG; ++c) o_acc[c] = (f32x4){0.f, 0.f, 0.f, 0.f};

  for (int kt0 = split * (NTOK / NSPLIT); kt0 < (split + 1) * (NTOK / NSPLIT); kt0 += KVB) {
    __syncthreads();
#pragma unroll
    for (int i = 0; i < KVB * DDIM / 2048; ++i) {
      int u = i * 256 + tid;
      int key = u / (DDIM / 8), part = u % (DDIM / 8);
      *(uint4*)&Ks[key * KSTR + part * 8] =
          *(const uint4*)&K[(size_t)(kt0 + key) * DDIM + part * 8];
    }
#pragma unroll
    for (int i = 0; i < KVB * DDIM / 2048; ++i) {
      int u = i * 256 + tid;
      int d = u / (KVB / 8), part = u % (KVB / 8);
      *(uint4*)&Vs[d * VSTR + part * 8] =
          *(const uint4*)&V[(size_t)d * NTOK + kt0 + part * 8];
    }
    __syncthreads();
    f32x4 s_acc[NT];
#pragma unroll
    for (int n = 0; n < NT; ++n) s_acc[n] = (f32x4){0.f, 0.f, 0.f, 0.f};
    __builtin_amdgcn_s_setprio(1);
#pragma unroll
    for (int n = 0; n < NT; ++n)
#pragma unroll
      for (int kc = 0; kc < KCH; ++kc) {
        bf16x8 kf = *(const bf16x8*)&Ks[(n * 16 + ll) * KSTR + kc * 32 + lg * 8];
        s_acc[n] = __builtin_amdgcn_mfma_f32_16x16x32_bf16(qf[kc], kf, s_acc[n], 0, 0, 0);
      }
    __builtin_amdgcn_s_setprio(0);
#pragma unroll
    for (int n = 0; n < NT; ++n)
#pragma unroll
      for (int r = 0; r < 4; ++r)
        Ps[(lg * 4 + r) * VSTR + n * 16 + ll] = f2bf(exp2f(s_acc[n][r]));
    __builtin_amdgcn_s_setprio(1);
#pragma unroll
    for (int pk = 0; pk < PKS; ++pk) {
      bf16x8 pa = *(const bf16x8*)&Ps[ll * VSTR + pk * 32 + lg * 8];
      lacc = __builtin_amdgcn_mfma_f32_16x16x32_bf16(pa, onesf, lacc, 0, 0, 0);
#pragma unroll
      for (int c = 0; c < OCG; ++c) {
        bf16x8 vf = *(const bf16x8*)&Vs[(c * 16 + ll) * VSTR + pk * 32 + lg * 8];
        o_acc[c] = __builtin_amdgcn_mfma_f32_16x16x32_bf16(pa, vf, o_acc[c], 0, 0, 0);
      }
    }
    __builtin_amdgcn_s_setprio(0);
  }
  if constexpr (NSPLIT > 1) {
    size_t ob = (size_t)(b * NSPLIT + split) * NTOK;
#pragma unroll
    for (int r = 0; r < 4; ++r) {
      int q = qw + lg * 4 + r;
#pragma unroll
      for (int c = 0; c < OCG; ++c)
        opart[(ob + q) * DDIM + c * 16 + ll] = f2bf(o_acc[c][r]);
      if (ll == 0) {
        ml[(ob + q) * 2]     = 0.f;
        ml[(ob + q) * 2 + 1] = lacc[r];
      }
    }
  } else {
#pragma unroll
    for (int r = 0; r < 4; ++r) {
      float inv = 1.0f / lacc[r];
      int q = qw + lg * 4 + r;
      int po = q / OW, qo = q % OW;
#pragma unroll
      for (int c = 0; c < OCG; ++c) {
        int d = c * 16 + ll;
        int ch = d / PP, rem = d % PP, y = rem / PW, x = rem % PW;
        int pos = (po * PH + y) * 64 + qo * PW + x;
        attbf[((size_t)b * NPOS + pos) * 256 + HEAD * 64 + ch] = f2bf(o_acc[c][r] * inv);
      }
    }
  }
}

// ---------------------------------------------------------------------------
// Head-3 flash, QBLK=128, staged K+V double-buffer, UNPADDED 128B rows with
// T2 XOR swizzle (chunk ^= row&7 on BOTH write and read — needed because
// 128B stride aliases all rows to bank 0; R20's mistake was XOR on an
// already-rotated 144B stride). LDS: 2*(8192K+8192V) + 8192P = 40960 B
// -> exactly 4 blocks/CU. kfr/vfr hoisted, shared by both Q groups (R23).
// Values bit-identical (slot permutation only).
__device__ __forceinline__ void flash3_dbuf(
    unsigned char* smem, int b, int q0, int split,
    const unsigned short* __restrict__ qt, const unsigned short* __restrict__ kt_,
    const unsigned short* __restrict__ vt, unsigned short* __restrict__ opart,
    float* __restrict__ ml) {
  const unsigned short* Q = qt + ((size_t)b * 4 + 3) * 262144;
  const unsigned short* K = kt_ + ((size_t)b * 4 + 3) * 262144;
  const unsigned short* V = vt + ((size_t)b * 4 + 3) * 262144;
  int tid = threadIdx.x;
  int wv = tid >> 6, l = tid & 63;
  int lg = l >> 4, ll = l & 15;
  int qwA = q0 + wv * 16;
  int qwB = qwA + 64;
  unsigned char* Psb = smem + 32768 + wv * 16 * 128;   // per-wave P tile

  bf16x8 qfA[2], qfB[2];
  qfA[0] = *(const bf16x8*)&Q[(size_t)(qwA + ll) * 64 + lg * 8];
  qfA[1] = *(const bf16x8*)&Q[(size_t)(qwA + ll) * 64 + 32 + lg * 8];
  qfB[0] = *(const bf16x8*)&Q[(size_t)(qwB + ll) * 64 + lg * 8];
  qfB[1] = *(const bf16x8*)&Q[(size_t)(qwB + ll) * 64 + 32 + lg * 8];

  bf16x8 onesf;
#pragma unroll
  for (int e = 0; e < 8; ++e) onesf[e] = (short)0x3F80;

  f32x4 laccA = (f32x4){0.f, 0.f, 0.f, 0.f};
  f32x4 laccB = (f32x4){0.f, 0.f, 0.f, 0.f};
  f32x4 o_accA[4], o_accB[4];
#pragma unroll
  for (int c = 0; c < 4; ++c) {
    o_accA[c] = (f32x4){0.f, 0.f, 0.f, 0.f};
    o_accB[c] = (f32x4){0.f, 0.f, 0.f, 0.f};
  }

  const int kstart = split * 1024, kend = kstart + 1024;

  {  // prologue: stage tile kstart into buffer 0 (swizzled chunk index)
    unsigned char* Kd = smem;
    unsigned char* Vd = smem + 8192;
#pragma unroll
    for (int i = 0; i < 2; ++i) {
      int u = i * 256 + tid, row = u >> 3, part = u & 7;
      int sw = (part ^ (row & 7)) * 16;
      *(uint4*)(Kd + row * 128 + sw) =
          *(const uint4*)&K[(size_t)(kstart + row) * 64 + part * 8];
      *(uint4*)(Vd + row * 128 + sw) =
          *(const uint4*)&V[(size_t)row * 4096 + kstart + part * 8];
    }
  }
  __syncthreads();

  int cur = 0;
  for (int kt0 = kstart; kt0 < kend; kt0 += 64) {
    const bool more = (kt0 + 64) < kend;
    if (more) {
      unsigned char* Kd = smem + (cur ^ 1) * 16384;
      unsigned char* Vd = Kd + 8192;
#pragma unroll
      for (int i = 0; i < 2; ++i) {
        int u = i * 256 + tid, row = u >> 3, part = u & 7;
        int sw = (part ^ (row & 7)) * 16;
        *(uint4*)(Kd + row * 128 + sw) =
            *(const uint4*)&K[(size_t)(kt0 + 64 + row) * 64 + part * 8];
        *(uint4*)(Vd + row * 128 + sw) =
            *(const uint4*)&V[(size_t)row * 4096 + (kt0 + 64) + part * 8];
      }
    }
    unsigned char* Kc = smem + cur * 16384;
    unsigned char* Vc = Kc + 8192;

    // hoist K/V fragments to registers once per tile (shared by A and B)
    bf16x8 kfr[4][2], vfr[2][4];
#pragma unroll
    for (int n = 0; n < 4; ++n)
#pragma unroll
      for (int kc = 0; kc < 2; ++kc)
        kfr[n][kc] = *(const bf16x8*)(Kc + (n * 16 + ll) * 128 +
                                      (((kc * 4 + lg) ^ (ll & 7)) * 16));
#pragma unroll
    for (int pk = 0; pk < 2; ++pk)
#pragma unroll
      for (int c = 0; c < 4; ++c)
        vfr[pk][c] = *(const bf16x8*)(Vc + (c * 16 + ll) * 128 +
                                      (((pk * 4 + lg) ^ (ll & 7)) * 16));

    // ---- group A ----
    {
      f32x4 s_acc[4];
#pragma unroll
      for (int n = 0; n < 4; ++n) s_acc[n] = (f32x4){0.f, 0.f, 0.f, 0.f};
      __builtin_amdgcn_s_setprio(1);
#pragma unroll
      for (int n = 0; n < 4; ++n)
#pragma unroll
        for (int kc = 0; kc < 2; ++kc)
          s_acc[n] = __builtin_amdgcn_mfma_f32_16x16x32_bf16(qfA[kc], kfr[n][kc], s_acc[n],
                                                             0, 0, 0);
      __builtin_amdgcn_s_setprio(0);
#pragma unroll
      for (int n = 0; n < 4; ++n)
#pragma unroll
        for (int r = 0; r < 4; ++r) {
          int prow = lg * 4 + r;
          int slot = (((n * 2 + (ll >> 3)) ^ (prow & 7)) << 3) + (ll & 7);
          *(unsigned short*)(Psb + prow * 128 + slot * 2) = f2bf(exp2f(s_acc[n][r]));
        }
      __builtin_amdgcn_s_setprio(1);
#pragma unroll
      for (int pk = 0; pk < 2; ++pk) {
        bf16x8 pa = *(const bf16x8*)(Psb + ll * 128 + (((pk * 4 + lg) ^ (ll & 7)) * 16));
        laccA = __builtin_amdgcn_mfma_f32_16x16x32_bf16(pa, onesf, laccA, 0, 0, 0);
#pragma unroll
        for (int c = 0; c < 4; ++c)
          o_accA[c] = __builtin_amdgcn_mfma_f32_16x16x32_bf16(pa, vfr[pk][c], o_accA[c],
                                                              0, 0, 0);
      }
      __builtin_amdgcn_s_setprio(0);
    }
    // ---- group B (reuses Ps after A's PV reads; same-wave DS ordering) ----
    {
      f32x4 s_acc[4];
#pragma unroll
      for (int n = 0; n < 4; ++n) s_acc[n] = (f32x4){0.f, 0.f, 0.f, 0.f};
      __builtin_amdgcn_s_setprio(1);
#pragma unroll
      for (int n = 0; n < 4; ++n)
#pragma unroll
        for (int kc = 0; kc < 2; ++kc)
          s_acc[n] = __builtin_amdgcn_mfma_f32_16x16x32_bf16(qfB[kc], kfr[n][kc], s_acc[n],
                                                             0, 0, 0);
      __builtin_amdgcn_s_setprio(0);
#pragma unroll
      for (int n = 0; n < 4; ++n)
#pragma unroll
        for (int r = 0; r < 4; ++r) {
          int prow = lg * 4 + r;
          int slot = (((n * 2 + (ll >> 3)) ^ (prow & 7)) << 3) + (ll & 7);
          *(unsigned short*)(Psb + prow * 128 + slot * 2) = f2bf(exp2f(s_acc[n][r]));
        }
      __builtin_amdgcn_s_setprio(1);
#pragma unroll
      for (int pk = 0; pk < 2; ++pk) {
        bf16x8 pa = *(const bf16x8*)(Psb + ll * 128 + (((pk * 4 + lg) ^ (ll & 7)) * 16));
        laccB = __builtin_amdgcn_mfma_f32_16x16x32_bf16(pa, onesf, laccB, 0, 0, 0);
#pragma unroll
        for (int c = 0; c < 4; ++c)
          o_accB[c] = __builtin_amdgcn_mfma_f32_16x16x32_bf16(pa, vfr[pk][c], o_accB[c],
                                                              0, 0, 0);
      }
      __builtin_amdgcn_s_setprio(0);
    }
    __syncthreads();
    cur ^= 1;
  }
  size_t ob = (size_t)(b * 4 + split) * 4096;
#pragma unroll
  for (int r = 0; r < 4; ++r) {
    int qA = qwA + lg * 4 + r;
    int qB = qwB + lg * 4 + r;
#pragma unroll
    for (int c = 0; c < 4; ++c) {
      opart[(ob + qA) * 64 + c * 16 + ll] = f2bf(o_accA[c][r]);
      opart[(ob + qB) * 64 + c * 16 + ll] = f2bf(o_accB[c][r]);
    }
    if (ll == 0) {
      ml[(ob + qA) * 2]     = 0.f;
      ml[(ob + qA) * 2 + 1] = laccA[r];
      ml[(ob + qB) * 2]     = 0.f;
      ml[(ob + qB) * 2 + 1] = laccB[r];
    }
  }
}

// ---------------------------------------------------------------------------
// Head 0/1 score bodies (proven round 13; h1 Kc split into 2x128-row halves
// — verified R24, bit-identical accumulation).
__device__ __forceinline__ void h0_score_body(unsigned char* smem, int b, int ds,
                                              const unsigned short* __restrict__ qt,
                                              const unsigned short* __restrict__ kt_,
                                              float* __restrict__ spart) {
  const unsigned short* Q = qt + ((size_t)b * 4 + 0) * 262144;
  const unsigned short* K = kt_ + ((size_t)b * 4 + 0) * 262144;
  unsigned short* Qc = (unsigned short*)smem;
  unsigned short* Kc = Qc + 64 * 72;
  int tid = threadIdx.x;
  int wv = tid >> 6, l = tid & 63;
  int lg = l >> 4, ll = l & 15;
  f32x4 s_acc[4];
#pragma unroll
  for (int n = 0; n < 4; ++n) s_acc[n] = (f32x4){0.f, 0.f, 0.f, 0.f};
  for (int ch = 0; ch < 8; ++ch) {
    int d0 = ds * 512 + ch * 64;
    __syncthreads();
#pragma unroll
    for (int i = 0; i < 2; ++i) {
      int u = i * 256 + tid, row = u >> 3, part = u & 7;
      *(uint4*)&Qc[row * 72 + part * 8] = *(const uint4*)&Q[(size_t)row * 4096 + d0 + part * 8];
      *(uint4*)&Kc[row * 72 + part * 8] = *(const uint4*)&K[(size_t)row * 4096 + d0 + part * 8];
    }
    __syncthreads();
#pragma unroll
    for (int n = 0; n < 4; ++n)
#pragma unroll
      for (int ks = 0; ks < 2; ++ks) {
        bf16x8 qa = *(const bf16x8*)&Qc[(wv * 16 + ll) * 72 + ks * 32 + lg * 8];
        bf16x8 kf = *(const bf16x8*)&Kc[(n * 16 + ll) * 72 + ks * 32 + lg * 8];
        s_acc[n] = __builtin_amdgcn_mfma_f32_16x16x32_bf16(qa, kf, s_acc[n], 0, 0, 0);
      }
  }
#pragma unroll
  for (int n = 0; n < 4; ++n)
#pragma unroll
    for (int r = 0; r < 4; ++r)
      spart[(((size_t)b * 8 + ds) * 64 + (wv * 16 + lg * 4 + r)) * 64 + n * 16 + ll] =
          s_acc[n][r];
}

__device__ __forceinline__ void h1_score_body(unsigned char* smem, int b, int qtile, int ds,
                                              const unsigned short* __restrict__ qt,
                                              const unsigned short* __restrict__ kt_,
                                              float* __restrict__ spart) {
  int q0 = qtile * 64, dbase = ds * 128;
  const unsigned short* Q = qt + ((size_t)b * 4 + 1) * 262144;
  const unsigned short* K = kt_ + ((size_t)b * 4 + 1) * 262144;
  unsigned short* Qc = (unsigned short*)smem;
  unsigned short* Kc = Qc + 64 * 72;   // 128 rows * 72 -> 27648 B total
  int tid = threadIdx.x;
  int wv = tid >> 6, l = tid & 63;
  int lg = l >> 4, ll = l & 15;
  f32x4 s_acc[16];
#pragma unroll
  for (int n = 0; n < 16; ++n) s_acc[n] = (f32x4){0.f, 0.f, 0.f, 0.f};
  for (int dc = 0; dc < 2; ++dc) {
    int d0 = dbase + dc * 64;
    for (int kh = 0; kh < 2; ++kh) {
      __syncthreads();
      if (kh == 0) {
#pragma unroll
        for (int i = 0; i < 2; ++i) {
          int u = i * 256 + tid, row = u >> 3, part = u & 7;
          *(uint4*)&Qc[row * 72 + part * 8] =
              *(const uint4*)&Q[(size_t)(q0 + row) * 1024 + d0 + part * 8];
        }
      }
#pragma unroll
      for (int i = 0; i < 4; ++i) {
        int u = i * 256 + tid, row = u >> 3, part = u & 7;
        *(uint4*)&Kc[row * 72 + part * 8] =
            *(const uint4*)&K[(size_t)(kh * 128 + row) * 1024 + d0 + part * 8];
      }
      __syncthreads();
#pragma unroll
      for (int ks = 0; ks < 2; ++ks) {
        bf16x8 qa = *(const bf16x8*)&Qc[(wv * 16 + ll) * 72 + ks * 32 + lg * 8];
#pragma unroll
        for (int nn = 0; nn < 8; ++nn) {
          bf16x8 kf = *(const bf16x8*)&Kc[(nn * 16 + ll) * 72 + ks * 32 + lg * 8];
          s_acc[kh * 8 + nn] = __builtin_amdgcn_mfma_f32_16x16x32_bf16(qa, kf, s_acc[kh * 8 + nn],
                                                                      0, 0, 0);
        }
      }
    }
  }
#pragma unroll
  for (int n = 0; n < 16; ++n)
#pragma unroll
    for (int r = 0; r < 4; ++r) {
      int q = q0 + wv * 16 + lg * 4 + r;
      spart[(((size_t)b * 8 + ds) * 256 + q) * 256 + n * 16 + ll] = s_acc[n][r];
    }
}

// ---------------------------------------------------------------------------
// Merged attention launch: flash3-dbuf QBLK=128 swz (bid<512) | flash2
// (512..639) | score01 (640..799). LDS 40960 B -> exactly 4 blocks/CU.
__global__ __launch_bounds__(256) void attn_all(
    const unsigned short* __restrict__ qt, const unsigned short* __restrict__ kt_,
    const unsigned short* __restrict__ vt,
    unsigned short* __restrict__ op2, float* __restrict__ ml2,
    unsigned short* __restrict__ op3, float* __restrict__ ml3,
    float* __restrict__ sp0, float* __restrict__ sp1,
    unsigned short* __restrict__ attbf) {
  __shared__ __align__(16) unsigned char smem[40960];
  int bid = blockIdx.x;
  if (bid < 512) {
    int b = bid & 3, qy = (bid >> 2) & 31, split = bid >> 7;
    flash3_dbuf(smem, b, qy * 128, split, qt, kt_, vt, op3, ml3);
  } else if (bid < 640) {
    int r = bid - 512;
    int b = r & 3, qy = (r >> 2) & 15, split = r >> 6;
    flash_body<1024, 256, 2, 32, 2, 2, 2>(smem, b, qy * 64, split, qt, kt_, vt,
                                          op2, ml2, attbf);
  } else {
    int r = bid - 640;
    if (r < 32) h0_score_body(smem, r >> 3, r & 7, qt, kt_, sp0);
    else {
      int rr = r - 32;
      h1_score_body(smem, rr >> 5, (rr >> 3) & 3, rr & 7, qt, kt_, sp1);
    }
  }
}

// ---------------------------------------------------------------------------
// Head 0/1 pv bodies (proven).
__device__ __forceinline__ void h0_pv_body(unsigned char* smem, int b, int ds,
                                           const float* __restrict__ spart,
                                           const unsigned short* __restrict__ vt,
                                           unsigned short* __restrict__ attbf) {
  const unsigned short* V = vt + ((size_t)b * 4 + 0) * 262144;
  float* S = (float*)smem;
  unsigned short* Ps = (unsigned short*)(smem + 16640);
  unsigned short* Vc = Ps + 64 * 72;
  int tid = threadIdx.x;
  int wv = tid >> 6, l = tid & 63;
  int lg = l >> 4, ll = l & 15;
#pragma unroll
  for (int i = 0; i < 16; ++i) {
    int idx = i * 256 + tid, q = idx >> 6, k = idx & 63;
    float s = 0.f;
#pragma unroll
    for (int sl = 0; sl < 8; ++sl)
      s += spart[(((size_t)b * 8 + sl) * 64 + q) * 64 + k];
    S[q * 65 + k] = s;
  }
  __syncthreads();
  for (int rr = 0; rr < 16; ++rr) {
    int row = wv * 16 + rr;
    float v = S[row * 65 + l] * 0.015625f;
    float m = v;
#pragma unroll
    for (int d = 32; d >= 1; d >>= 1) m = fmaxf(m, __shfl_xor(m, d));
    float p = __expf(v - m);
    float su = p;
#pragma unroll
    for (int d = 32; d >= 1; d >>= 1) su += __shfl_xor(su, d);
    Ps[row * 72 + l] = f2bf(p / su);
  }
  __syncthreads();
  for (int ch = 0; ch < 8; ++ch) {
    int d0 = ds * 512 + ch * 64;
    __syncthreads();
#pragma unroll
    for (int i = 0; i < 2; ++i) {
      int u = i * 256 + tid, row = u >> 3, part = u & 7;
      *(uint4*)&Vc[row * 72 + part * 8] =
          *(const uint4*)&V[(size_t)(d0 + row) * 64 + part * 8];
    }
    __syncthreads();
    f32x4 o[4];
#pragma unroll
    for (int cg = 0; cg < 4; ++cg) o[cg] = (f32x4){0.f, 0.f, 0.f, 0.f};
#pragma unroll
    for (int cg = 0; cg < 4; ++cg)
#pragma unroll
      for (int ks = 0; ks < 2; ++ks) {
        bf16x8 pa = *(const bf16x8*)&Ps[(wv * 16 + ll) * 72 + ks * 32 + lg * 8];
        bf16x8 vf = *(const bf16x8*)&Vc[(cg * 16 + ll) * 72 + ks * 32 + lg * 8];
        o[cg] = __builtin_amdgcn_mfma_f32_16x16x32_bf16(pa, vf, o[cg], 0, 0, 0);
      }
#pragma unroll
    for (int cg = 0; cg < 4; ++cg)
#pragma unroll
      for (int r = 0; r < 4; ++r) {
        int q = wv * 16 + lg * 4 + r;
        int d = d0 + cg * 16 + ll;
        int c = d >> 6, rem = d & 63, y = rem >> 3, x = rem & 7;
        int po = q >> 3, qo = q & 7;
        int pos = (po * 8 + y) * 64 + qo * 8 + x;
        attbf[((size_t)b * NPOS + pos) * 256 + c] = f2bf(o[cg][r]);
      }
  }
}

__device__ __forceinline__ void h1_pv_body(unsigned char* smem, int b, int qtile, int vs,
                                           const float* __restrict__ spart,
                                           const unsigned short* __restrict__ vt,
                                           unsigned short* __restrict__ attbf) {
  int q0 = qtile * 64, dv0 = vs * 128;
  const unsigned short* V = vt + ((size_t)b * 4 + 1) * 262144;
  unsigned short* Ps = (unsigned short*)smem;
  unsigned short* Vs = Ps + 64 * 264;
  int tid = threadIdx.x;
  int wv = tid >> 6, l = tid & 63;
  int lg = l >> 4, ll = l & 15;
  for (int rr = 0; rr < 16; ++rr) {
    int row = q0 + wv * 16 + rr;
    float sv[4];
#pragma unroll
    for (int c4 = 0; c4 < 4; ++c4) {
      float s = 0.f;
#pragma unroll
      for (int sl = 0; sl < 8; ++sl)
        s += spart[(((size_t)b * 8 + sl) * 256 + row) * 256 + c4 * 64 + l];
      sv[c4] = s * 0.03125f;
    }
    float m = fmaxf(fmaxf(sv[0], sv[1]), fmaxf(sv[2], sv[3]));
#pragma unroll
    for (int d = 32; d >= 1; d >>= 1) m = fmaxf(m, __shfl_xor(m, d));
    float p[4], su = 0.f;
#pragma unroll
    for (int c4 = 0; c4 < 4; ++c4) { p[c4] = __expf(sv[c4] - m); su += p[c4]; }
#pragma unroll
    for (int d = 32; d >= 1; d >>= 1) su += __shfl_xor(su, d);
    float inv = 1.0f / su;
#pragma unroll
    for (int c4 = 0; c4 < 4; ++c4)
      Ps[(wv * 16 + rr) * 264 + c4 * 64 + l] = f2bf(p[c4] * inv);
  }
  for (int vc = 0; vc < 4; ++vc) {
    int d0 = dv0 + vc * 32;
    __syncthreads();
#pragma unroll
    for (int i = 0; i < 4; ++i) {
      int u = i * 256 + tid, row = u >> 5, part = u & 31;
      *(uint4*)&Vs[row * 264 + part * 8] =
          *(const uint4*)&V[(size_t)(d0 + row) * 256 + part * 8];
    }
    __syncthreads();
    f32x4 o[2];
    o[0] = (f32x4){0.f, 0.f, 0.f, 0.f};
    o[1] = (f32x4){0.f, 0.f, 0.f, 0.f};
#pragma unroll
    for (int ks = 0; ks < 8; ++ks) {
      bf16x8 pa = *(const bf16x8*)&Ps[(wv * 16 + ll) * 264 + ks * 32 + lg * 8];
#pragma unroll
      for (int cg = 0; cg < 2; ++cg) {
        bf16x8 vf = *(const bf16x8*)&Vs[(cg * 16 + ll) * 264 + ks * 32 + lg * 8];
        o[cg] = __builtin_amdgcn_mfma_f32_16x16x32_bf16(pa, vf, o[cg], 0, 0, 0);
      }
    }
#pragma unroll
    for (int cg = 0; cg < 2; ++cg)
#pragma unroll
      for (int r = 0; r < 4; ++r) {
        int q = q0 + wv * 16 + lg * 4 + r;
        int d = d0 + cg * 16 + ll;
        int c = d >> 4, rem = d & 15, y = rem >> 2, x = rem & 3;
        int po = q >> 4, qo = q & 15;
        int pos = (po * 4 + y) * 64 + qo * 4 + x;
        attbf[((size_t)b * NPOS + pos) * 256 + 64 + c] = f2bf(o[cg][r]);
      }
  }
}

// ---------------------------------------------------------------------------
// Merged finish launch: pv01 (bid<160) | combine23 (160..8351), bf16 partials.
__global__ __launch_bounds__(256) void finish_all(
    const float* __restrict__ sp0, const float* __restrict__ sp1,
    const unsigned short* __restrict__ op2, const float* __restrict__ ml2,
    const unsigned short* __restrict__ op3, const float* __restrict__ ml3,
    const unsigned short* __restrict__ vt, unsigned short* __restrict__ attbf) {
  __shared__ __align__(16) unsigned char smem[50688];
  int bid = blockIdx.x;
  if (bid < 32) { h0_pv_body(smem, bid >> 3, bid & 7, sp0, vt, attbf); return; }
  if (bid < 160) {
    int r = bid - 32;
    h1_pv_body(smem, r >> 5, (r >> 3) & 3, r & 7, sp1, vt, attbf);
    return;
  }
  int cb = bid - 160;
  if (cb < 4096) {  // head 2, NSPLIT=2
    int b = cb >> 10, q = cb & 1023;
    int d = threadIdx.x;
    float num = 0.f, den = 0.f;
#pragma unroll
    for (int s = 0; s < 2; ++s) {
      den += ml2[((size_t)(b * 2 + s) * 1024 + q) * 2 + 1];
      num += bf2f(op2[((size_t)(b * 2 + s) * 1024 + q) * 256 + d]);
    }
    int c = d >> 2, rem = d & 3, y = rem >> 1, x = rem & 1;
    int po = q >> 5, qo = q & 31;
    int pos = (po * 2 + y) * 64 + qo * 2 + x;
    attbf[((size_t)b * NPOS + pos) * 256 + 128 + c] = f2bf(num / den);
  } else {           // head 3, NSPLIT=4
    cb -= 4096;
    int b = cb >> 10, qt4 = cb & 1023;
    int q = qt4 * 4 + (threadIdx.x >> 6), ch = threadIdx.x & 63;
    float num = 0.f, den = 0.f;
#pragma unroll
    for (int s = 0; s < 4; ++s) {
      den += ml3[((size_t)(b * 4 + s) * 4096 + q) * 2 + 1];
      num += bf2f(op3[((size_t)(b * 4 + s) * 4096 + q) * 64 + ch]);
    }
    attbf[((size_t)b * 4096 + q) * 256 + 192 + ch] = f2bf(num / den);
  }
}

// ---------------------------------------------------------------------------
// 3x3 SAME conv (bf16 MFMA implicit GEMM) + BN + LeakyReLU(0.2). (round 17)
__global__ __launch_bounds__(512) void conv_mfma(
    const unsigned short* __restrict__ attbf, const unsigned short* __restrict__ w2,
    const float* __restrict__ bo, const float* __restrict__ gamma,
    const float* __restrict__ beta, const float* __restrict__ rmean,
    const float* __restrict__ rvar, float* __restrict__ out) {
  int hq = blockIdx.x, ot = blockIdx.y, b = blockIdx.z;
  int h0 = hq * 4, o0 = ot * 64;
  __shared__ unsigned short As[4 * 66 * 72];
  __shared__ unsigned short Ws[3 * 64 * 72];
  int tid = threadIdx.x;
  int wi = tid >> 6, l = tid & 63;
  int hrow = wi >> 1, wseg = wi & 1;
  int lg = l >> 4, ll = l & 15;
  const size_t attb = (size_t)b * NPOS * 256;
  f32x4 acc[4][2];
#pragma unroll
  for (int mi = 0; mi < 4; ++mi)
#pragma unroll
    for (int ni = 0; ni < 2; ++ni) acc[mi][ni] = (f32x4){0.f, 0.f, 0.f, 0.f};

  for (int dy = 0; dy < 3; ++dy) {
    for (int c0 = 0; c0 < 256; c0 += 64) {
      __syncthreads();
      if (tid < 256) {
        int rowl = tid >> 6, w = tid & 63;
        int ghh = h0 + dy - 1 + rowl;
        uint4 z = make_uint4(0u, 0u, 0u, 0u);
        uint4 a[8];
        if (ghh >= 0 && ghh < 64) {
          const uint4* src = (const uint4*)(attbf + attb + ((size_t)(ghh * 64 + w) * 256 + c0));
#pragma unroll
          for (int q = 0; q < 8; ++q) a[q] = src[q];
        } else {
#pragma unroll
          for (int q = 0; q < 8; ++q) a[q] = z;
        }
        uint4* dst = (uint4*)&As[(rowl * 66 + 1 + w) * 72];
#pragma unroll
        for (int q = 0; q < 8; ++q) dst[q] = a[q];
        if (w == 0 || w == 63) {
          uint4* dz = (uint4*)&As[(rowl * 66 + ((w == 0) ? 0 : 65)) * 72];
#pragma unroll
          for (int q = 0; q < 8; ++q) dz[q] = z;
        }
      } else {
        int p = tid - 256;
        int dx = p >> 6, ol = p & 63;
        if (dx < 3) {
          const uint4* src = (const uint4*)(w2 + ((size_t)(dy * 3 + dx) * 65536 +
                                                  (size_t)(o0 + ol) * 256 + c0));
          uint4* dst = (uint4*)&Ws[(dx * 64 + ol) * 72];
#pragma unroll
          for (int q = 0; q < 8; ++q) dst[q] = src[q];
        }
      }
      __syncthreads();
#pragma unroll
      for (int dx = 0; dx < 3; ++dx) {
#pragma unroll
        for (int ks = 0; ks < 2; ++ks) {
          bf16x8 af[4];
#pragma unroll
          for (int mi = 0; mi < 4; ++mi)
            af[mi] = *(const bf16x8*)&Ws[(dx * 64 + mi * 16 + ll) * 72 + ks * 32 + lg * 8];
#pragma unroll
          for (int ni = 0; ni < 2; ++ni) {
            bf16x8 bfr = *(const bf16x8*)&As[(hrow * 66 + wseg * 32 + ni * 16 + ll + dx) * 72 +
                                             ks * 32 + lg * 8];
#pragma unroll
            for (int mi = 0; mi < 4; ++mi)
              acc[mi][ni] = __builtin_amdgcn_mfma_f32_16x16x32_bf16(af[mi], bfr, acc[mi][ni],
                                                                    0, 0, 0);
          }
        }
      }
    }
  }
  int h = h0 + hrow;
#pragma unroll
  for (int mi = 0; mi < 4; ++mi) {
#pragma unroll
    for (int r = 0; r < 4; ++r) {
      int o = o0 + mi * 16 + lg * 4 + r;
      float g  = gamma[o] * rsqrtf(rvar[o] + 1e-5f);
      float bb = (bo[o] - rmean[o]) * g + beta[o];
#pragma unroll
      for (int ni = 0; ni < 2; ++ni) {
        float zv = acc[mi][ni][r] * g + bb;
        zv = (zv >= 0.f) ? zv : 0.2f * zv;
        out[((size_t)(b * 256 + o)) * NPOS + h * 64 + wseg * 32 + ni * 16 + ll] = zv;
      }
    }
  }
}

// ---------------------------------------------------------------------------
extern "C" void kernel_launch(void* const* d_in, const int* in_sizes, int n_in,
                              void* d_out, int out_size, void* d_ws, size_t ws_size,
                              hipStream_t stream) {
  (void)in_sizes; (void)n_in; (void)out_size; (void)ws_size;
  const float* x     = (const float*)d_in[0];
  const float* Wq    = (const float*)d_in[1];
  const float* bq    = (const float*)d_in[2];
  const float* Wk    = (const float*)d_in[3];
  const float* bk    = (const float*)d_in[4];
  const float* Wv    = (const float*)d_in[5];
  const float* bv    = (const float*)d_in[6];
  const float* Wo    = (const float*)d_in[7];
  const float* bo    = (const float*)d_in[8];
  const float* gamma = (const float*)d_in[9];
  const float* beta  = (const float*)d_in[10];
  const float* rmean = (const float*)d_in[11];
  const float* rvar  = (const float*)d_in[12];
  float* ws  = (float*)d_ws;
  float* out = (float*)d_out;
  unsigned short* attbf = (unsigned short*)(ws + AOFF);
  unsigned short* w2bf  = (unsigned short*)(ws + WTOFF);
  unsigned short* qt    = (unsigned short*)(ws + QTOFF);
  unsigned short* kt    = (unsigned short*)(ws + KTOFF);
  unsigned short* vt    = (unsigned short*)(ws + VTOFF);
  unsigned short* op2   = (unsigned short*)(ws + OP2OFF);
  unsigned short* op3   = (unsigned short*)(ws + OP3OFF);

  // QKV projections writing q_t/k_t/v_t directly (+ Wo transpose, z=12)
  qkv_fused<<<dim3(64, 4, 13), 256, 0, stream>>>(x, Wq, Wk, Wv, bq, bk, bv,
                                                 Wo, w2bf, qt, kt, vt);

  // all attention compute co-scheduled: flash3 (QBLK=128, staged K+V swz,
  // 4 blocks/CU) | flash2 | score01
  attn_all<<<800, 256, 0, stream>>>(qt, kt, vt,
                                    op2, ws + ML2OFF,
                                    op3, ws + ML3OFF,
                                    ws + SP0OFF, ws + SP1OFF, attbf);

  // all finish work co-scheduled: pv01 | combine23
  finish_all<<<8352, 256, 0, stream>>>(ws + SP0OFF, ws + SP1OFF,
                                       op2, ws + ML2OFF,
                                       op3, ws + ML3OFF, vt, attbf);

  conv_mfma<<<dim3(16, 4, 4), 512, 0, stream>>>(attbf, w2bf, bo, gamma, beta,
                                                rmean, rvar, out);
}

// Round 26
// 173.519 us; speedup vs baseline: 1.2158x; 1.1537x over previous
//
#include <hip/hip_runtime.h>
#include <hip/hip_bf16.h>
#include <math.h>

// Problem constants: b=4, C=256, H=W=64
#define NPOS 4096
#define CPB  1048576
// ws layout (float offsets)
#define QOFF  ((size_t)0)          // v_t bf16 (2.097M fl) + ml3 + ml2
#define KOFF  ((size_t)4194304)    // head3 opart bf16
#define VOFF  ((size_t)8388608)    // h1 spart (2M fl) + head2 opart bf16
#define AOFF  ((size_t)12582912)   // bf16 att, [b][pos][c]
#define S0OFF ((size_t)16777216)   // q_t + k_t + h0 Spart
#define WTOFF ((size_t)21250048)   // bf16 W2 [k][o][c]
#define QTOFF   S0OFF
#define KTOFF   (S0OFF + (size_t)2097152)
#define SP0OFF  (S0OFF + (size_t)4194304)
#define VTOFF   QOFF
#define ML3OFF  (QOFF + (size_t)2097152)
#define ML2OFF  (QOFF + (size_t)2228224)
#define OP3OFF  KOFF
#define SP1OFF  VOFF
#define OP2OFF  (VOFF + (size_t)2097152)

#define LOG2E 1.44269504088896340736f

typedef __attribute__((ext_vector_type(8))) short bf16x8;
typedef __attribute__((ext_vector_type(4))) float f32x4;

static __device__ __forceinline__ unsigned short f2bf(float f) {
  __hip_bfloat16 h = __float2bfloat16(f);
  unsigned short u;
  __builtin_memcpy(&u, &h, sizeof(u));
  return u;
}

static __device__ __forceinline__ float bf2f(unsigned short u) {
  unsigned v = ((unsigned)u) << 16;
  float f;
  __builtin_memcpy(&f, &v, sizeof(f));
  return f;
}

// ---------------------------------------------------------------------------
// Scatter helpers (proven round 13).
template<int PH, int PW>
__device__ __forceinline__ void scat_qk(unsigned short* __restrict__ dst,
                                        const unsigned short* __restrict__ Ac,
                                        int gh, int tid) {
  constexpr int PP = PH * PW, OW = 64 / PW, D = 64 * PP;
  int po = gh / PH, y = gh % PH;
  constexpr int NCH = 64 * OW;
#pragma unroll
  for (int j = 0; j < NCH / 256; ++j) {
    int id = j * 256 + tid;
    int c = id / OW, qo = id % OW;
    int tt = po * OW + qo;
    unsigned short buf[PW];
#pragma unroll
    for (int x = 0; x < PW; ++x) buf[x] = Ac[c * 66 + qo * PW + x];
    unsigned short* dp = &dst[(size_t)tt * D + c * PP + y * PW];
    if constexpr (PW == 8)      { uint4 v;  __builtin_memcpy(&v, buf, 16); *(uint4*)dp = v; }
    else if constexpr (PW == 4) { uint2 v;  __builtin_memcpy(&v, buf, 8);  *(uint2*)dp = v; }
    else                        { unsigned v; __builtin_memcpy(&v, buf, 4); *(unsigned*)dp = v; }
  }
}

template<int PH, int PW>
__device__ __forceinline__ void scat_v(unsigned short* __restrict__ dst,
                                       const unsigned short* __restrict__ Ac,
                                       int gh, int tid) {
  constexpr int PP = PH * PW, OW = 64 / PW, NT = 4096 / PP;
  int po = gh / PH, y = gh % PH;
  constexpr int NCH = 64 * PW;
  constexpr int CPT = (NCH + 255) / 256;
#pragma unroll
  for (int j = 0; j < CPT; ++j) {
    int id = j * 256 + tid;
    if (NCH < 256 && id >= NCH) break;
    int c = id / PW, x = id % PW;
    int d = c * PP + y * PW + x;
    unsigned short* dp = &dst[(size_t)d * NT + po * OW];
#pragma unroll
    for (int s = 0; s < OW; s += 8) {
      unsigned short buf[8];
#pragma unroll
      for (int e = 0; e < 8; ++e) buf[e] = Ac[c * 66 + (s + e) * PW + x];
      uint4 v; __builtin_memcpy(&v, buf, 16);
      *(uint4*)&dp[s] = v;
    }
  }
}

// ---------------------------------------------------------------------------
// Fused QKV projections (q pre-scaled for heads 2/3) + Wo transpose (z=12).
// grid (64 rows, 4 heads, 13). (proven round 17)
__global__ __launch_bounds__(256) void qkv_fused(
    const float* __restrict__ x,
    const float* __restrict__ Wq, const float* __restrict__ Wk, const float* __restrict__ Wv,
    const float* __restrict__ bq, const float* __restrict__ bk, const float* __restrict__ bv,
    const float* __restrict__ Wo, unsigned short* __restrict__ W2,
    unsigned short* __restrict__ qt, unsigned short* __restrict__ kt_,
    unsigned short* __restrict__ vt) {
  if (blockIdx.z == 12) {
    int o = blockIdx.y * 64 + blockIdx.x;
    size_t base = (size_t)o * 2304;
#pragma unroll
    for (int r = 0; r < 9; ++r) {
      int rr = r * 256 + threadIdx.x;
      int c = rr / 9, k = rr % 9;
      W2[(size_t)k * 65536 + (size_t)o * 256 + c] = f2bf(Wo[base + rr]);
    }
    return;
  }
  int b = blockIdx.z / 3, t = blockIdx.z % 3;
  const float* W    = (t == 0) ? Wq : (t == 1) ? Wk : Wv;
  const float* bias = (t == 0) ? bq : (t == 1) ? bk : bv;
  int h = blockIdx.y, gh = blockIdx.x;
  int o0 = h * 64, p0 = gh * 64;
  __shared__ unsigned short smem[2 * 64 * 72];
  unsigned short* Wt = smem;
  unsigned short* Xs = smem + 64 * 72;
  int tid = threadIdx.x;
  int wv = tid >> 6, l = tid & 63;
  int lg = l >> 4, ll = l & 15;
  f32x4 acc[4];
#pragma unroll
  for (int mi = 0; mi < 4; ++mi) acc[mi] = (f32x4){0.f, 0.f, 0.f, 0.f};

  int wol = tid >> 2, wcp = (tid & 3) * 16;
  int xcc = tid >> 6, xpz = tid & 63;

  for (int c0 = 0; c0 < 256; c0 += 64) {
    __syncthreads();
#pragma unroll
    for (int u = 0; u < 4; ++u) {
      float4 w4 = *(const float4*)&W[(size_t)(o0 + wol) * 256 + c0 + wcp + u * 4];
      ushort4 pk;
      pk.x = f2bf(w4.x); pk.y = f2bf(w4.y); pk.z = f2bf(w4.z); pk.w = f2bf(w4.w);
      *(ushort4*)&Wt[wol * 72 + wcp + u * 4] = pk;
    }
#pragma unroll
    for (int r = 0; r < 16; ++r) {
      int c = xcc * 16 + r;
      Xs[xpz * 72 + c] = f2bf(x[(size_t)b * CPB + (size_t)(c0 + c) * NPOS + p0 + xpz]);
    }
    __syncthreads();
#pragma unroll
    for (int ks = 0; ks < 2; ++ks) {
      bf16x8 xb = *(const bf16x8*)&Xs[(wv * 16 + ll) * 72 + ks * 32 + lg * 8];
#pragma unroll
      for (int mi = 0; mi < 4; ++mi) {
        bf16x8 wa = *(const bf16x8*)&Wt[(mi * 16 + ll) * 72 + ks * 32 + lg * 8];
        acc[mi] = __builtin_amdgcn_mfma_f32_16x16x32_bf16(wa, xb, acc[mi], 0, 0, 0);
      }
    }
  }
  __syncthreads();
  float qs = 1.0f;
  if (t == 0) qs = (h == 2) ? 0.0625f * LOG2E : (h == 3) ? 0.125f * LOG2E : 1.0f;
  unsigned short* Ac = smem;
#pragma unroll
  for (int mi = 0; mi < 4; ++mi)
#pragma unroll
    for (int r = 0; r < 4; ++r) {
      int ol = mi * 16 + lg * 4 + r;
      Ac[ol * 66 + wv * 16 + ll] = f2bf((acc[mi][r] + bias[o0 + ol]) * qs);
    }
  __syncthreads();
  if (t < 2) {
    unsigned short* dst = (t == 0 ? qt : kt_) + ((size_t)b * 4 + h) * 262144;
    switch (h) {
      case 0: scat_qk<8, 8>(dst, Ac, gh, tid); break;
      case 1: scat_qk<4, 4>(dst, Ac, gh, tid); break;
      case 2: scat_qk<2, 2>(dst, Ac, gh, tid); break;
      default: {
        int p = tid >> 2, c0 = (tid & 3) * 16;
        unsigned short buf[16];
#pragma unroll
        for (int e = 0; e < 16; ++e) buf[e] = Ac[(c0 + e) * 66 + p];
        uint4 v0, v1;
        __builtin_memcpy(&v0, buf, 16);
        __builtin_memcpy(&v1, buf + 8, 16);
        uint4* d4 = (uint4*)&dst[(size_t)(gh * 64 + p) * 64 + c0];
        d4[0] = v0; d4[1] = v1;
      } break;
    }
  } else {
    unsigned short* dst = vt + ((size_t)b * 4 + h) * 262144;
    switch (h) {
      case 0: scat_v<8, 8>(dst, Ac, gh, tid); break;
      case 1: scat_v<4, 4>(dst, Ac, gh, tid); break;
      case 2: scat_v<2, 2>(dst, Ac, gh, tid); break;
      default: {
        if (tid < 64) {
#pragma unroll
          for (int seg = 0; seg < 8; ++seg) {
            unsigned short buf[8];
#pragma unroll
            for (int e = 0; e < 8; ++e) buf[e] = Ac[tid * 66 + seg * 8 + e];
            uint4 v; __builtin_memcpy(&v, buf, 16);
            *(uint4*)&dst[(size_t)tid * 4096 + gh * 64 + seg * 8] = v;
          }
        }
      } break;
    }
  }
}

// ---------------------------------------------------------------------------
// Flash attention body (single-buffer LDS staging, used by flash2 only).
// Bare-exp2 softmax (Q pre-scaled); setprio; bf16 split partials.
template<int NTOK, int DDIM, int NSPLIT, int KVB, int PH, int PW, int HEAD>
__device__ __forceinline__ void flash_body(
    unsigned char* smem, int b, int q0, int split,
    const unsigned short* __restrict__ qt, const unsigned short* __restrict__ kt_,
    const unsigned short* __restrict__ vt, unsigned short* __restrict__ opart,
    float* __restrict__ ml, unsigned short* __restrict__ attbf) {
  constexpr int KSTR = DDIM + 8;
  constexpr int VSTR = KVB + 8;
  constexpr int NT   = KVB / 16;
  constexpr int KCH  = DDIM / 32;
  constexpr int PKS  = KVB / 32;
  constexpr int OCG  = DDIM / 16;
  constexpr int PP = PH * PW, OW = 64 / PW;
  const unsigned short* Q = qt + ((size_t)b * 4 + HEAD) * 262144;
  const unsigned short* K = kt_ + ((size_t)b * 4 + HEAD) * 262144;
  const unsigned short* V = vt + ((size_t)b * 4 + HEAD) * 262144;
  unsigned short* Ks = (unsigned short*)smem;
  unsigned short* Vs = Ks + KVB * KSTR;
  unsigned short* Psw = Vs + DDIM * VSTR;
  int tid = threadIdx.x;
  int wv = tid >> 6, l = tid & 63;
  int lg = l >> 4, ll = l & 15;
  int qw = q0 + wv * 16;
  unsigned short* Ps = Psw + wv * 16 * VSTR;

  bf16x8 qf[KCH];
#pragma unroll
  for (int kc = 0; kc < KCH; ++kc)
    qf[kc] = *(const bf16x8*)&Q[(size_t)(qw + ll) * DDIM + kc * 32 + lg * 8];

  bf16x8 onesf;
#pragma unroll
  for (int e = 0; e < 8; ++e) onesf[e] = (short)0x3F80;

  f32x4 lacc = (f32x4){0.f, 0.f, 0.f, 0.f};
  f32x4 o_acc[OCG];
#pragma unroll
  for (int c = 0; c < OCG; ++c) o_acc[c] = (f32x4){0.f, 0.f, 0.f, 0.f};

  for (int kt0 = split * (NTOK / NSPLIT); kt0 < (split + 1) * (NTOK / NSPLIT); kt0 += KVB) {
    __syncthreads();
#pragma unroll
    for (int i = 0; i < KVB * DDIM / 2048; ++i) {
      int u = i * 256 + tid;
      int key = u / (DDIM / 8), part = u % (DDIM / 8);
      *(uint4*)&Ks[key * KSTR + part * 8] =
          *(const uint4*)&K[(size_t)(kt0 + key) * DDIM + part * 8];
    }
#pragma unroll
    for (int i = 0; i < KVB * DDIM / 2048; ++i) {
      int u = i * 256 + tid;
      int d = u / (KVB / 8), part = u % (KVB / 8);
      *(uint4*)&Vs[d * VSTR + part * 8] =
          *(const uint4*)&V[(size_t)d * NTOK + kt0 + part * 8];
    }
    __syncthreads();
    f32x4 s_acc[NT];
#pragma unroll
    for (int n = 0; n < NT; ++n) s_acc[n] = (f32x4){0.f, 0.f, 0.f, 0.f};
    __builtin_amdgcn_s_setprio(1);
#pragma unroll
    for (int n = 0; n < NT; ++n)
#pragma unroll
      for (int kc = 0; kc < KCH; ++kc) {
        bf16x8 kf = *(const bf16x8*)&Ks[(n * 16 + ll) * KSTR + kc * 32 + lg * 8];
        s_acc[n] = __builtin_amdgcn_mfma_f32_16x16x32_bf16(qf[kc], kf, s_acc[n], 0, 0, 0);
      }
    __builtin_amdgcn_s_setprio(0);
#pragma unroll
    for (int n = 0; n < NT; ++n)
#pragma unroll
      for (int r = 0; r < 4; ++r)
        Ps[(lg * 4 + r) * VSTR + n * 16 + ll] = f2bf(exp2f(s_acc[n][r]));
    __builtin_amdgcn_s_setprio(1);
#pragma unroll
    for (int pk = 0; pk < PKS; ++pk) {
      bf16x8 pa = *(const bf16x8*)&Ps[ll * VSTR + pk * 32 + lg * 8];
      lacc = __builtin_amdgcn_mfma_f32_16x16x32_bf16(pa, onesf, lacc, 0, 0, 0);
#pragma unroll
      for (int c = 0; c < OCG; ++c) {
        bf16x8 vf = *(const bf16x8*)&Vs[(c * 16 + ll) * VSTR + pk * 32 + lg * 8];
        o_acc[c] = __builtin_amdgcn_mfma_f32_16x16x32_bf16(pa, vf, o_acc[c], 0, 0, 0);
      }
    }
    __builtin_amdgcn_s_setprio(0);
  }
  if constexpr (NSPLIT > 1) {
    size_t ob = (size_t)(b * NSPLIT + split) * NTOK;
#pragma unroll
    for (int r = 0; r < 4; ++r) {
      int q = qw + lg * 4 + r;
#pragma unroll
      for (int c = 0; c < OCG; ++c)
        opart[(ob + q) * DDIM + c * 16 + ll] = f2bf(o_acc[c][r]);
      if (ll == 0) {
        ml[(ob + q) * 2]     = 0.f;
        ml[(ob + q) * 2 + 1] = lacc[r];
      }
    }
  } else {
#pragma unroll
    for (int r = 0; r < 4; ++r) {
      float inv = 1.0f / lacc[r];
      int q = qw + lg * 4 + r;
      int po = q / OW, qo = q % OW;
#pragma unroll
      for (int c = 0; c < OCG; ++c) {
        int d = c * 16 + ll;
        int ch = d / PP, rem = d % PP, y = rem / PW, x = rem % PW;
        int pos = (po * PH + y) * 64 + qo * PW + x;
        attbf[((size_t)b * NPOS + pos) * 256 + HEAD * 64 + ch] = f2bf(o_acc[c][r] * inv);
      }
    }
  }
}

// ---------------------------------------------------------------------------
// Head-3 flash, LDS double-buffer, QBLK=128 + register-hoisted K/V fragments:
// kfr/vfr loaded from LDS ONCE per tile and reused by both Q groups (A, B) —
// halves LDS b128 read traffic (36 -> 20 per tile per wave). (round 23 best)
__device__ __forceinline__ void flash3_dbuf(
    unsigned char* smem, int b, int q0, int split,
    const unsigned short* __restrict__ qt, const unsigned short* __restrict__ kt_,
    const unsigned short* __restrict__ vt, unsigned short* __restrict__ opart,
    float* __restrict__ ml) {
  const unsigned short* Q = qt + ((size_t)b * 4 + 3) * 262144;
  const unsigned short* K = kt_ + ((size_t)b * 4 + 3) * 262144;
  const unsigned short* V = vt + ((size_t)b * 4 + 3) * 262144;
  int tid = threadIdx.x;
  int wv = tid >> 6, l = tid & 63;
  int lg = l >> 4, ll = l & 15;
  int qwA = q0 + wv * 16;
  int qwB = qwA + 64;
  unsigned short* Ps = (unsigned short*)(smem + 36864) + wv * 16 * 72;

  bf16x8 qfA[2], qfB[2];
  qfA[0] = *(const bf16x8*)&Q[(size_t)(qwA + ll) * 64 + lg * 8];
  qfA[1] = *(const bf16x8*)&Q[(size_t)(qwA + ll) * 64 + 32 + lg * 8];
  qfB[0] = *(const bf16x8*)&Q[(size_t)(qwB + ll) * 64 + lg * 8];
  qfB[1] = *(const bf16x8*)&Q[(size_t)(qwB + ll) * 64 + 32 + lg * 8];

  bf16x8 onesf;
#pragma unroll
  for (int e = 0; e < 8; ++e) onesf[e] = (short)0x3F80;

  f32x4 laccA = (f32x4){0.f, 0.f, 0.f, 0.f};
  f32x4 laccB = (f32x4){0.f, 0.f, 0.f, 0.f};
  f32x4 o_accA[4], o_accB[4];
#pragma unroll
  for (int c = 0; c < 4; ++c) {
    o_accA[c] = (f32x4){0.f, 0.f, 0.f, 0.f};
    o_accB[c] = (f32x4){0.f, 0.f, 0.f, 0.f};
  }

  const int kstart = split * 1024, kend = kstart + 1024;

  {  // prologue: stage tile kstart into buffer 0
    unsigned short* Kd = (unsigned short*)smem;
    unsigned short* Vd = Kd + 4608;
#pragma unroll
    for (int i = 0; i < 2; ++i) {
      int u = i * 256 + tid, row = u >> 3, part = u & 7;
      *(uint4*)&Kd[row * 72 + part * 8] =
          *(const uint4*)&K[(size_t)(kstart + row) * 64 + part * 8];
      *(uint4*)&Vd[row * 72 + part * 8] =
          *(const uint4*)&V[(size_t)row * 4096 + kstart + part * 8];
    }
  }
  __syncthreads();

  int cur = 0;
  for (int kt0 = kstart; kt0 < kend; kt0 += 64) {
    const bool more = (kt0 + 64) < kend;
    if (more) {
      unsigned short* Kd = (unsigned short*)(smem + (cur ^ 1) * 18432);
      unsigned short* Vd = Kd + 4608;
#pragma unroll
      for (int i = 0; i < 2; ++i) {
        int u = i * 256 + tid, row = u >> 3, part = u & 7;
        *(uint4*)&Kd[row * 72 + part * 8] =
            *(const uint4*)&K[(size_t)(kt0 + 64 + row) * 64 + part * 8];
        *(uint4*)&Vd[row * 72 + part * 8] =
            *(const uint4*)&V[(size_t)row * 4096 + (kt0 + 64) + part * 8];
      }
    }
    unsigned short* Kc = (unsigned short*)(smem + cur * 18432);
    unsigned short* Vc = Kc + 4608;

    // hoist K/V fragments to registers once per tile (shared by A and B)
    bf16x8 kfr[4][2], vfr[2][4];
#pragma unroll
    for (int n = 0; n < 4; ++n)
#pragma unroll
      for (int kc = 0; kc < 2; ++kc)
        kfr[n][kc] = *(const bf16x8*)&Kc[(n * 16 + ll) * 72 + kc * 32 + lg * 8];
#pragma unroll
    for (int pk = 0; pk < 2; ++pk)
#pragma unroll
      for (int c = 0; c < 4; ++c)
        vfr[pk][c] = *(const bf16x8*)&Vc[(c * 16 + ll) * 72 + pk * 32 + lg * 8];

    // ---- group A ----
    {
      f32x4 s_acc[4];
#pragma unroll
      for (int n = 0; n < 4; ++n) s_acc[n] = (f32x4){0.f, 0.f, 0.f, 0.f};
      __builtin_amdgcn_s_setprio(1);
#pragma unroll
      for (int n = 0; n < 4; ++n)
#pragma unroll
        for (int kc = 0; kc < 2; ++kc)
          s_acc[n] = __builtin_amdgcn_mfma_f32_16x16x32_bf16(qfA[kc], kfr[n][kc], s_acc[n],
                                                             0, 0, 0);
      __builtin_amdgcn_s_setprio(0);
#pragma unroll
      for (int n = 0; n < 4; ++n)
#pragma unroll
        for (int r = 0; r < 4; ++r)
          Ps[(lg * 4 + r) * 72 + n * 16 + ll] = f2bf(exp2f(s_acc[n][r]));
      __builtin_amdgcn_s_setprio(1);
#pragma unroll
      for (int pk = 0; pk < 2; ++pk) {
        bf16x8 pa = *(const bf16x8*)&Ps[ll * 72 + pk * 32 + lg * 8];
        laccA = __builtin_amdgcn_mfma_f32_16x16x32_bf16(pa, onesf, laccA, 0, 0, 0);
#pragma unroll
        for (int c = 0; c < 4; ++c)
          o_accA[c] = __builtin_amdgcn_mfma_f32_16x16x32_bf16(pa, vfr[pk][c], o_accA[c],
                                                              0, 0, 0);
      }
      __builtin_amdgcn_s_setprio(0);
    }
    // ---- group B (reuses Ps after A's PV reads; same-wave DS ordering) ----
    {
      f32x4 s_acc[4];
#pragma unroll
      for (int n = 0; n < 4; ++n) s_acc[n] = (f32x4){0.f, 0.f, 0.f, 0.f};
      __builtin_amdgcn_s_setprio(1);
#pragma unroll
      for (int n = 0; n < 4; ++n)
#pragma unroll
        for (int kc = 0; kc < 2; ++kc)
          s_acc[n] = __builtin_amdgcn_mfma_f32_16x16x32_bf16(qfB[kc], kfr[n][kc], s_acc[n],
                                                             0, 0, 0);
      __builtin_amdgcn_s_setprio(0);
#pragma unroll
      for (int n = 0; n < 4; ++n)
#pragma unroll
        for (int r = 0; r < 4; ++r)
          Ps[(lg * 4 + r) * 72 + n * 16 + ll] = f2bf(exp2f(s_acc[n][r]));
      __builtin_amdgcn_s_setprio(1);
#pragma unroll
      for (int pk = 0; pk < 2; ++pk) {
        bf16x8 pa = *(const bf16x8*)&Ps[ll * 72 + pk * 32 + lg * 8];
        laccB = __builtin_amdgcn_mfma_f32_16x16x32_bf16(pa, onesf, laccB, 0, 0, 0);
#pragma unroll
        for (int c = 0; c < 4; ++c)
          o_accB[c] = __builtin_amdgcn_mfma_f32_16x16x32_bf16(pa, vfr[pk][c], o_accB[c],
                                                              0, 0, 0);
      }
      __builtin_amdgcn_s_setprio(0);
    }
    __syncthreads();
    cur ^= 1;
  }
  size_t ob = (size_t)(b * 4 + split) * 4096;
#pragma unroll
  for (int r = 0; r < 4; ++r) {
    int qA = qwA + lg * 4 + r;
    int qB = qwB + lg * 4 + r;
#pragma unroll
    for (int c = 0; c < 4; ++c) {
      opart[(ob + qA) * 64 + c * 16 + ll] = f2bf(o_accA[c][r]);
      opart[(ob + qB) * 64 + c * 16 + ll] = f2bf(o_accB[c][r]);
    }
    if (ll == 0) {
      ml[(ob + qA) * 2]     = 0.f;
      ml[(ob + qA) * 2 + 1] = laccA[r];
      ml[(ob + qB) * 2]     = 0.f;
      ml[(ob + qB) * 2 + 1] = laccB[r];
    }
  }
}

// ---------------------------------------------------------------------------
// Head 0/1 score bodies (proven round 13).
__device__ __forceinline__ void h0_score_body(unsigned char* smem, int b, int ds,
                                              const unsigned short* __restrict__ qt,
                                              const unsigned short* __restrict__ kt_,
                                              float* __restrict__ spart) {
  const unsigned short* Q = qt + ((size_t)b * 4 + 0) * 262144;
  const unsigned short* K = kt_ + ((size_t)b * 4 + 0) * 262144;
  unsigned short* Qc = (unsigned short*)smem;
  unsigned short* Kc = Qc + 64 * 72;
  int tid = threadIdx.x;
  int wv = tid >> 6, l = tid & 63;
  int lg = l >> 4, ll = l & 15;
  f32x4 s_acc[4];
#pragma unroll
  for (int n = 0; n < 4; ++n) s_acc[n] = (f32x4){0.f, 0.f, 0.f, 0.f};
  for (int ch = 0; ch < 8; ++ch) {
    int d0 = ds * 512 + ch * 64;
    __syncthreads();
#pragma unroll
    for (int i = 0; i < 2; ++i) {
      int u = i * 256 + tid, row = u >> 3, part = u & 7;
      *(uint4*)&Qc[row * 72 + part * 8] = *(const uint4*)&Q[(size_t)row * 4096 + d0 + part * 8];
      *(uint4*)&Kc[row * 72 + part * 8] = *(const uint4*)&K[(size_t)row * 4096 + d0 + part * 8];
    }
    __syncthreads();
#pragma unroll
    for (int n = 0; n < 4; ++n)
#pragma unroll
      for (int ks = 0; ks < 2; ++ks) {
        bf16x8 qa = *(const bf16x8*)&Qc[(wv * 16 + ll) * 72 + ks * 32 + lg * 8];
        bf16x8 kf = *(const bf16x8*)&Kc[(n * 16 + ll) * 72 + ks * 32 + lg * 8];
        s_acc[n] = __builtin_amdgcn_mfma_f32_16x16x32_bf16(qa, kf, s_acc[n], 0, 0, 0);
      }
  }
#pragma unroll
  for (int n = 0; n < 4; ++n)
#pragma unroll
    for (int r = 0; r < 4; ++r)
      spart[(((size_t)b * 8 + ds) * 64 + (wv * 16 + lg * 4 + r)) * 64 + n * 16 + ll] =
          s_acc[n][r];
}

__device__ __forceinline__ void h1_score_body(unsigned char* smem, int b, int qtile, int ds,
                                              const unsigned short* __restrict__ qt,
                                              const unsigned short* __restrict__ kt_,
                                              float* __restrict__ spart) {
  int q0 = qtile * 64, dbase = ds * 128;
  const unsigned short* Q = qt + ((size_t)b * 4 + 1) * 262144;
  const unsigned short* K = kt_ + ((size_t)b * 4 + 1) * 262144;
  unsigned short* Qc = (unsigned short*)smem;
  unsigned short* Kc = Qc + 64 * 72;   // 256*72
  int tid = threadIdx.x;
  int wv = tid >> 6, l = tid & 63;
  int lg = l >> 4, ll = l & 15;
  f32x4 s_acc[16];
#pragma unroll
  for (int n = 0; n < 16; ++n) s_acc[n] = (f32x4){0.f, 0.f, 0.f, 0.f};
  for (int dc = 0; dc < 2; ++dc) {
    int d0 = dbase + dc * 64;
    __syncthreads();
#pragma unroll
    for (int i = 0; i < 2; ++i) {
      int u = i * 256 + tid, row = u >> 3, part = u & 7;
      *(uint4*)&Qc[row * 72 + part * 8] =
          *(const uint4*)&Q[(size_t)(q0 + row) * 1024 + d0 + part * 8];
    }
#pragma unroll
    for (int i = 0; i < 8; ++i) {
      int u = i * 256 + tid, row = u >> 3, part = u & 7;
      *(uint4*)&Kc[row * 72 + part * 8] =
          *(const uint4*)&K[(size_t)row * 1024 + d0 + part * 8];
    }
    __syncthreads();
#pragma unroll
    for (int ks = 0; ks < 2; ++ks) {
      bf16x8 qa = *(const bf16x8*)&Qc[(wv * 16 + ll) * 72 + ks * 32 + lg * 8];
#pragma unroll
      for (int n = 0; n < 16; ++n) {
        bf16x8 kf = *(const bf16x8*)&Kc[(n * 16 + ll) * 72 + ks * 32 + lg * 8];
        s_acc[n] = __builtin_amdgcn_mfma_f32_16x16x32_bf16(qa, kf, s_acc[n], 0, 0, 0);
      }
    }
  }
#pragma unroll
  for (int n = 0; n < 16; ++n)
#pragma unroll
    for (int r = 0; r < 4; ++r) {
      int q = q0 + wv * 16 + lg * 4 + r;
      spart[(((size_t)b * 8 + ds) * 256 + q) * 256 + n * 16 + ll] = s_acc[n][r];
    }
}

// ---------------------------------------------------------------------------
// Merged attention launch: flash3-dbuf QBLK=128 (bid<512) | flash2
// (512..639) | score01 (640..799).
__global__ __launch_bounds__(256) void attn_all(
    const unsigned short* __restrict__ qt, const unsigned short* __restrict__ kt_,
    const unsigned short* __restrict__ vt,
    unsigned short* __restrict__ op2, float* __restrict__ ml2,
    unsigned short* __restrict__ op3, float* __restrict__ ml3,
    float* __restrict__ sp0, float* __restrict__ sp1,
    unsigned short* __restrict__ attbf) {
  __shared__ __align__(16) unsigned char smem[46080];
  int bid = blockIdx.x;
  if (bid < 512) {
    int b = bid & 3, qy = (bid >> 2) & 31, split = bid >> 7;
    flash3_dbuf(smem, b, qy * 128, split, qt, kt_, vt, op3, ml3);
  } else if (bid < 640) {
    int r = bid - 512;
    int b = r & 3, qy = (r >> 2) & 15, split = r >> 6;
    flash_body<1024, 256, 2, 32, 2, 2, 2>(smem, b, qy * 64, split, qt, kt_, vt,
                                          op2, ml2, attbf);
  } else {
    int r = bid - 640;
    if (r < 32) h0_score_body(smem, r >> 3, r & 7, qt, kt_, sp0);
    else {
      int rr = r - 32;
      h1_score_body(smem, rr >> 5, (rr >> 3) & 3, rr & 7, qt, kt_, sp1);
    }
  }
}

// ---------------------------------------------------------------------------
// Head 0/1 pv bodies (proven).
__device__ __forceinline__ void h0_pv_body(unsigned char* smem, int b, int ds,
                                           const float* __restrict__ spart,
                                           const unsigned short* __restrict__ vt,
                                           unsigned short* __restrict__ attbf) {
  const unsigned short* V = vt + ((size_t)b * 4 + 0) * 262144;
  float* S = (float*)smem;
  unsigned short* Ps = (unsigned short*)(smem + 16640);
  unsigned short* Vc = Ps + 64 * 72;
  int tid = threadIdx.x;
  int wv = tid >> 6, l = tid & 63;
  int lg = l >> 4, ll = l & 15;
#pragma unroll
  for (int i = 0; i < 16; ++i) {
    int idx = i * 256 + tid, q = idx >> 6, k = idx & 63;
    float s = 0.f;
#pragma unroll
    for (int sl = 0; sl < 8; ++sl)
      s += spart[(((size_t)b * 8 + sl) * 64 + q) * 64 + k];
    S[q * 65 + k] = s;
  }
  __syncthreads();
  for (int rr = 0; rr < 16; ++rr) {
    int row = wv * 16 + rr;
    float v = S[row * 65 + l] * 0.015625f;
    float m = v;
#pragma unroll
    for (int d = 32; d >= 1; d >>= 1) m = fmaxf(m, __shfl_xor(m, d));
    float p = __expf(v - m);
    float su = p;
#pragma unroll
    for (int d = 32; d >= 1; d >>= 1) su += __shfl_xor(su, d);
    Ps[row * 72 + l] = f2bf(p / su);
  }
  __syncthreads();
  for (int ch = 0; ch < 8; ++ch) {
    int d0 = ds * 512 + ch * 64;
    __syncthreads();
#pragma unroll
    for (int i = 0; i < 2; ++i) {
      int u = i * 256 + tid, row = u >> 3, part = u & 7;
      *(uint4*)&Vc[row * 72 + part * 8] =
          *(const uint4*)&V[(size_t)(d0 + row) * 64 + part * 8];
    }
    __syncthreads();
    f32x4 o[4];
#pragma unroll
    for (int cg = 0; cg < 4; ++cg) o[cg] = (f32x4){0.f, 0.f, 0.f, 0.f};
#pragma unroll
    for (int cg = 0; cg < 4; ++cg)
#pragma unroll
      for (int ks = 0; ks < 2; ++ks) {
        bf16x8 pa = *(const bf16x8*)&Ps[(wv * 16 + ll) * 72 + ks * 32 + lg * 8];
        bf16x8 vf = *(const bf16x8*)&Vc[(cg * 16 + ll) * 72 + ks * 32 + lg * 8];
        o[cg] = __builtin_amdgcn_mfma_f32_16x16x32_bf16(pa, vf, o[cg], 0, 0, 0);
      }
#pragma unroll
    for (int cg = 0; cg < 4; ++cg)
#pragma unroll
      for (int r = 0; r < 4; ++r) {
        int q = wv * 16 + lg * 4 + r;
        int d = d0 + cg * 16 + ll;
        int c = d >> 6, rem = d & 63, y = rem >> 3, x = rem & 7;
        int po = q >> 3, qo = q & 7;
        int pos = (po * 8 + y) * 64 + qo * 8 + x;
        attbf[((size_t)b * NPOS + pos) * 256 + c] = f2bf(o[cg][r]);
      }
  }
}

__device__ __forceinline__ void h1_pv_body(unsigned char* smem, int b, int qtile, int vs,
                                           const float* __restrict__ spart,
                                           const unsigned short* __restrict__ vt,
                                           unsigned short* __restrict__ attbf) {
  int q0 = qtile * 64, dv0 = vs * 128;
  const unsigned short* V = vt + ((size_t)b * 4 + 1) * 262144;
  unsigned short* Ps = (unsigned short*)smem;
  unsigned short* Vs = Ps + 64 * 264;
  int tid = threadIdx.x;
  int wv = tid >> 6, l = tid & 63;
  int lg = l >> 4, ll = l & 15;
  for (int rr = 0; rr < 16; ++rr) {
    int row = q0 + wv * 16 + rr;
    float sv[4];
#pragma unroll
    for (int c4 = 0; c4 < 4; ++c4) {
      float s = 0.f;
#pragma unroll
      for (int sl = 0; sl < 8; ++sl)
        s += spart[(((size_t)b * 8 + sl) * 256 + row) * 256 + c4 * 64 + l];
      sv[c4] = s * 0.03125f;
    }
    float m = fmaxf(fmaxf(sv[0], sv[1]), fmaxf(sv[2], sv[3]));
#pragma unroll
    for (int d = 32; d >= 1; d >>= 1) m = fmaxf(m, __shfl_xor(m, d));
    float p[4], su = 0.f;
#pragma unroll
    for (int c4 = 0; c4 < 4; ++c4) { p[c4] = __expf(sv[c4] - m); su += p[c4]; }
#pragma unroll
    for (int d = 32; d >= 1; d >>= 1) su += __shfl_xor(su, d);
    float inv = 1.0f / su;
#pragma unroll
    for (int c4 = 0; c4 < 4; ++c4)
      Ps[(wv * 16 + rr) * 264 + c4 * 64 + l] = f2bf(p[c4] * inv);
  }
  for (int vc = 0; vc < 4; ++vc) {
    int d0 = dv0 + vc * 32;
    __syncthreads();
#pragma unroll
    for (int i = 0; i < 4; ++i) {
      int u = i * 256 + tid, row = u >> 5, part = u & 31;
      *(uint4*)&Vs[row * 264 + part * 8] =
          *(const uint4*)&V[(size_t)(d0 + row) * 256 + part * 8];
    }
    __syncthreads();
    f32x4 o[2];
    o[0] = (f32x4){0.f, 0.f, 0.f, 0.f};
    o[1] = (f32x4){0.f, 0.f, 0.f, 0.f};
#pragma unroll
    for (int ks = 0; ks < 8; ++ks) {
      bf16x8 pa = *(const bf16x8*)&Ps[(wv * 16 + ll) * 264 + ks * 32 + lg * 8];
#pragma unroll
      for (int cg = 0; cg < 2; ++cg) {
        bf16x8 vf = *(const bf16x8*)&Vs[(cg * 16 + ll) * 264 + ks * 32 + lg * 8];
        o[cg] = __builtin_amdgcn_mfma_f32_16x16x32_bf16(pa, vf, o[cg], 0, 0, 0);
      }
    }
#pragma unroll
    for (int cg = 0; cg < 2; ++cg)
#pragma unroll
      for (int r = 0; r < 4; ++r) {
        int q = q0 + wv * 16 + lg * 4 + r;
        int d = d0 + cg * 16 + ll;
        int c = d >> 4, rem = d & 15, y = rem >> 2, x = rem & 3;
        int po = q >> 4, qo = q & 15;
        int pos = (po * 4 + y) * 64 + qo * 4 + x;
        attbf[((size_t)b * NPOS + pos) * 256 + 64 + c] = f2bf(o[cg][r]);
      }
  }
}

// ---------------------------------------------------------------------------
// Merged finish launch: pv01 (bid<160) | combine23 (160..8351), bf16 partials.
__global__ __launch_bounds__(256) void finish_all(
    const float* __restrict__ sp0, const float* __restrict__ sp1,
    const unsigned short* __restrict__ op2, const float* __restrict__ ml2,
    const unsigned short* __restrict__ op3, const float* __restrict__ ml3,
    const unsigned short* __restrict__ vt, unsigned short* __restrict__ attbf) {
  __shared__ __align__(16) unsigned char smem[50688];
  int bid = blockIdx.x;
  if (bid < 32) { h0_pv_body(smem, bid >> 3, bid & 7, sp0, vt, attbf); return; }
  if (bid < 160) {
    int r = bid - 32;
    h1_pv_body(smem, r >> 5, (r >> 3) & 3, r & 7, sp1, vt, attbf);
    return;
  }
  int cb = bid - 160;
  if (cb < 4096) {  // head 2, NSPLIT=2
    int b = cb >> 10, q = cb & 1023;
    int d = threadIdx.x;
    float num = 0.f, den = 0.f;
#pragma unroll
    for (int s = 0; s < 2; ++s) {
      den += ml2[((size_t)(b * 2 + s) * 1024 + q) * 2 + 1];
      num += bf2f(op2[((size_t)(b * 2 + s) * 1024 + q) * 256 + d]);
    }
    int c = d >> 2, rem = d & 3, y = rem >> 1, x = rem & 1;
    int po = q >> 5, qo = q & 31;
    int pos = (po * 2 + y) * 64 + qo * 2 + x;
    attbf[((size_t)b * NPOS + pos) * 256 + 128 + c] = f2bf(num / den);
  } else {           // head 3, NSPLIT=4
    cb -= 4096;
    int b = cb >> 10, qt4 = cb & 1023;
    int q = qt4 * 4 + (threadIdx.x >> 6), ch = threadIdx.x & 63;
    float num = 0.f, den = 0.f;
#pragma unroll
    for (int s = 0; s < 4; ++s) {
      den += ml3[((size_t)(b * 4 + s) * 4096 + q) * 2 + 1];
      num += bf2f(op3[((size_t)(b * 4 + s) * 4096 + q) * 64 + ch]);
    }
    attbf[((size_t)b * 4096 + q) * 256 + 192 + ch] = f2bf(num / den);
  }
}

// ---------------------------------------------------------------------------
// 3x3 SAME conv (bf16 MFMA implicit GEMM) + BN + LeakyReLU(0.2). (round 17)
__global__ __launch_bounds__(512) void conv_mfma(
    const unsigned short* __restrict__ attbf, const unsigned short* __restrict__ w2,
    const float* __restrict__ bo, const float* __restrict__ gamma,
    const float* __restrict__ beta, const float* __restrict__ rmean,
    const float* __restrict__ rvar, float* __restrict__ out) {
  int hq = blockIdx.x, ot = blockIdx.y, b = blockIdx.z;
  int h0 = hq * 4, o0 = ot * 64;
  __shared__ unsigned short As[4 * 66 * 72];
  __shared__ unsigned short Ws[3 * 64 * 72];
  int tid = threadIdx.x;
  int wi = tid >> 6, l = tid & 63;
  int hrow = wi >> 1, wseg = wi & 1;
  int lg = l >> 4, ll = l & 15;
  const size_t attb = (size_t)b * NPOS * 256;
  f32x4 acc[4][2];
#pragma unroll
  for (int mi = 0; mi < 4; ++mi)
#pragma unroll
    for (int ni = 0; ni < 2; ++ni) acc[mi][ni] = (f32x4){0.f, 0.f, 0.f, 0.f};

  for (int dy = 0; dy < 3; ++dy) {
    for (int c0 = 0; c0 < 256; c0 += 64) {
      __syncthreads();
      if (tid < 256) {
        int rowl = tid >> 6, w = tid & 63;
        int ghh = h0 + dy - 1 + rowl;
        uint4 z = make_uint4(0u, 0u, 0u, 0u);
        uint4 a[8];
        if (ghh >= 0 && ghh < 64) {
          const uint4* src = (const uint4*)(attbf + attb + ((size_t)(ghh * 64 + w) * 256 + c0));
#pragma unroll
          for (int q = 0; q < 8; ++q) a[q] = src[q];
        } else {
#pragma unroll
          for (int q = 0; q < 8; ++q) a[q] = z;
        }
        uint4* dst = (uint4*)&As[(rowl * 66 + 1 + w) * 72];
#pragma unroll
        for (int q = 0; q < 8; ++q) dst[q] = a[q];
        if (w == 0 || w == 63) {
          uint4* dz = (uint4*)&As[(rowl * 66 + ((w == 0) ? 0 : 65)) * 72];
#pragma unroll
          for (int q = 0; q < 8; ++q) dz[q] = z;
        }
      } else {
        int p = tid - 256;
        int dx = p >> 6, ol = p & 63;
        if (dx < 3) {
          const uint4* src = (const uint4*)(w2 + ((size_t)(dy * 3 + dx) * 65536 +
                                                  (size_t)(o0 + ol) * 256 + c0));
          uint4* dst = (uint4*)&Ws[(dx * 64 + ol) * 72];
#pragma unroll
          for (int q = 0; q < 8; ++q) dst[q] = src[q];
        }
      }
      __syncthreads();
#pragma unroll
      for (int dx = 0; dx < 3; ++dx) {
#pragma unroll
        for (int ks = 0; ks < 2; ++ks) {
          bf16x8 af[4];
#pragma unroll
          for (int mi = 0; mi < 4; ++mi)
            af[mi] = *(const bf16x8*)&Ws[(dx * 64 + mi * 16 + ll) * 72 + ks * 32 + lg * 8];
#pragma unroll
          for (int ni = 0; ni < 2; ++ni) {
            bf16x8 bfr = *(const bf16x8*)&As[(hrow * 66 + wseg * 32 + ni * 16 + ll + dx) * 72 +
                                             ks * 32 + lg * 8];
#pragma unroll
            for (int mi = 0; mi < 4; ++mi)
              acc[mi][ni] = __builtin_amdgcn_mfma_f32_16x16x32_bf16(af[mi], bfr, acc[mi][ni],
                                                                    0, 0, 0);
          }
        }
      }
    }
  }
  int h = h0 + hrow;
#pragma unroll
  for (int mi = 0; mi < 4; ++mi) {
#pragma unroll
    for (int r = 0; r < 4; ++r) {
      int o = o0 + mi * 16 + lg * 4 + r;
      float g  = gamma[o] * rsqrtf(rvar[o] + 1e-5f);
      float bb = (bo[o] - rmean[o]) * g + beta[o];
#pragma unroll
      for (int ni = 0; ni < 2; ++ni) {
        float zv = acc[mi][ni][r] * g + bb;
        zv = (zv >= 0.f) ? zv : 0.2f * zv;
        out[((size_t)(b * 256 + o)) * NPOS + h * 64 + wseg * 32 + ni * 16 + ll] = zv;
      }
    }
  }
}

// ---------------------------------------------------------------------------
extern "C" void kernel_launch(void* const* d_in, const int* in_sizes, int n_in,
                              void* d_out, int out_size, void* d_ws, size_t ws_size,
                              hipStream_t stream) {
  (void)in_sizes; (void)n_in; (void)out_size; (void)ws_size;
  const float* x     = (const float*)d_in[0];
  const float* Wq    = (const float*)d_in[1];
  const float* bq    = (const float*)d_in[2];
  const float* Wk    = (const float*)d_in[3];
  const float* bk    = (const float*)d_in[4];
  const float* Wv    = (const float*)d_in[5];
  const float* bv    = (const float*)d_in[6];
  const float* Wo    = (const float*)d_in[7];
  const float* bo    = (const float*)d_in[8];
  const float* gamma = (const float*)d_in[9];
  const float* beta  = (const float*)d_in[10];
  const float* rmean = (const float*)d_in[11];
  const float* rvar  = (const float*)d_in[12];
  float* ws  = (float*)d_ws;
  float* out = (float*)d_out;
  unsigned short* attbf = (unsigned short*)(ws + AOFF);
  unsigned short* w2bf  = (unsigned short*)(ws + WTOFF);
  unsigned short* qt    = (unsigned short*)(ws + QTOFF);
  unsigned short* kt    = (unsigned short*)(ws + KTOFF);
  unsigned short* vt    = (unsigned short*)(ws + VTOFF);
  unsigned short* op2   = (unsigned short*)(ws + OP2OFF);
  unsigned short* op3   = (unsigned short*)(ws + OP3OFF);

  // QKV projections writing q_t/k_t/v_t directly (+ Wo transpose, z=12)
  qkv_fused<<<dim3(64, 4, 13), 256, 0, stream>>>(x, Wq, Wk, Wv, bq, bk, bv,
                                                 Wo, w2bf, qt, kt, vt);

  // all attention compute co-scheduled: flash3 (QBLK=128, reg-hoisted K/V) |
  // flash2 | score01
  attn_all<<<800, 256, 0, stream>>>(qt, kt, vt,
                                    op2, ws + ML2OFF,
                                    op3, ws + ML3OFF,
                                    ws + SP0OFF, ws + SP1OFF, attbf);

  // all finish work co-scheduled: pv01 | combine23
  finish_all<<<8352, 256, 0, stream>>>(ws + SP0OFF, ws + SP1OFF,
                                       op2, ws + ML2OFF,
                                       op3, ws + ML3OFF, vt, attbf);

  conv_mfma<<<dim3(16, 4, 4), 512, 0, stream>>>(attbf, w2bf, bo, gamma, beta,
                                                rmean, rvar, out);
}